// Round 11
// baseline (359.143 us; speedup 1.0000x reference)
//
#include <hip/hip_runtime.h>
#include <math.h>

#define TT 16
#define HH 112
#define WD 112
#define CC 96
#define NHEADS 3
#define HD 32
#define NN 98          // window tokens 2*7*7
#define NWIN 2048      // 8*16*16
#define NTOK 200704    // T*H*W == NWIN*NN
#define MLPH 384
#define SXP 104        // row stride (bf16) LDS tiles (208B rows, 16B aligned)
#define SQP 40         // row stride (bf16) per-head sQ/sK
#define SVP 136        // row stride (bf16) sVt/sP
#define SHP 392        // row stride (bf16) sH full (384 cols + 8 pad)
#define SX1P 100       // row stride (bf16) sX1

typedef unsigned int  u32;
typedef unsigned short u16;
typedef float f32x4 __attribute__((ext_vector_type(4)));
typedef short bf16x8 __attribute__((ext_vector_type(8)));

__device__ inline u16 f2bf(float f) {
  u32 u = __float_as_uint(f);
  u += 0x7fffu + ((u >> 16) & 1u);
  return (u16)(u >> 16);
}
__device__ inline float bflo(u32 u) { return __uint_as_float(u << 16); }
__device__ inline float bfhi(u32 u) { return __uint_as_float(u & 0xffff0000u); }

#define MFMA16(a, b, c) __builtin_amdgcn_mfma_f32_16x16x32_bf16((a), (b), (c), 0, 0, 0)

// ---------------- K0a: transpose all weights to bf16 col-major ----------------
__global__ __launch_bounds__(256) void wprep_kernel(
    const float* __restrict__ qkv_w, const float* __restrict__ proj_w,
    const float* __restrict__ fc1_w, const float* __restrict__ fc2_w,
    u16* __restrict__ qkv_wT, u16* __restrict__ proj_wT,
    u16* __restrict__ fc1_wT, u16* __restrict__ fc2_wT) {
  int idx = blockIdx.x * 256 + threadIdx.x;
  if (idx < 27648) {                       // qkv_wT[col][c]
    int col = idx / CC, c = idx - col * CC;
    qkv_wT[idx] = f2bf(qkv_w[c * (3 * CC) + col]);
    return;
  }
  idx -= 27648;
  if (idx < 9216) {                        // proj_wT[col][c]
    int col = idx / CC, c = idx - col * CC;
    proj_wT[idx] = f2bf(proj_w[c * CC + col]);
    return;
  }
  idx -= 9216;
  if (idx < 36864) {                       // fc1_wT[j][c]
    int j = idx / CC, c = idx - j * CC;
    fc1_wT[idx] = f2bf(fc1_w[c * MLPH + j]);
    return;
  }
  idx -= 36864;
  if (idx < 36864) {                       // fc2_wT[c][j]
    int c = idx / MLPH, j = idx - c * MLPH;
    fc2_wT[idx] = f2bf(fc2_w[j * CC + c]);
  }
}

// ---------------- K0b: biasT[head][q][kv] = rpb[ridx(q,kv)*3+head] ----------------
__global__ __launch_bounds__(256) void bias_kernel(const float* __restrict__ rpb,
                                                   float* __restrict__ biasT) {
  int idx = blockIdx.x * 256 + threadIdx.x;
  if (idx >= NHEADS * NN * NN) return;
  int head = idx / (NN * NN);
  int r = idx - head * NN * NN;
  int q = r / NN, kv = r - q * NN;
  int itq = q / 49, rq = q - itq * 49, ihq = rq / 7, iwq = rq - ihq * 7;
  int itk = kv / 49, rk = kv - itk * 49, ihk = rk / 7, iwk = rk - ihk * 7;
  int ridx = (itq - itk + 1) * 169 + (ihq - ihk + 6) * 13 + (iwq - iwk + 6);
  biasT[idx] = rpb[ridx * NHEADS + head];
}

// ---------------- K0c: LN1 + shift-roll + window gather -> xnw[widx][112][96] bf16 ----------------
__global__ __launch_bounds__(256) void ln1_kernel(
    const float* __restrict__ x, const float* __restrict__ g1, const float* __restrict__ b1,
    u16* __restrict__ xnw)
{
  const int tid = threadIdx.x;
  const int row = blockIdx.x * 64 + (tid >> 2);   // 0 .. NWIN*112-1
  const int qd = tid & 3;                          // quarter: 24 channels
  const int widx = row / 112;
  const int n = row - widx * 112;
  u16* dst = xnw + (size_t)row * CC + qd * 24;
  if (n >= NN) {                                   // pad row -> zeros
    uint4 z = {0u, 0u, 0u, 0u};
    *(uint4*)(dst) = z; *(uint4*)(dst + 8) = z; *(uint4*)(dst + 16) = z;
    return;
  }
  int it = n / 49, r = n - it * 49, ih = r / 7, iw = r - ih * 7;
  int ww = widx & 15, hw = (widx >> 4) & 15, tw = widx >> 8;
  int t = tw * 2 + it + 1; if (t >= TT) t -= TT;
  int h = hw * 7 + ih + 3; if (h >= HH) h -= HH;
  int w = ww * 7 + iw + 3; if (w >= WD) w -= WD;
  const float* src = x + ((size_t)(t * HH + h) * WD + w) * CC + qd * 24;
  float v[24];
  #pragma unroll
  for (int i = 0; i < 24; i += 4) {
    float4 f = *(const float4*)(src + i);
    v[i] = f.x; v[i + 1] = f.y; v[i + 2] = f.z; v[i + 3] = f.w;
  }
  float sm = 0.f;
  #pragma unroll
  for (int i = 0; i < 24; ++i) sm += v[i];
  sm += __shfl_xor(sm, 1, 64);
  sm += __shfl_xor(sm, 2, 64);
  float mu = sm * (1.f / CC);
  float sq = 0.f;
  #pragma unroll
  for (int i = 0; i < 24; ++i) { float d = v[i] - mu; sq += d * d; }
  sq += __shfl_xor(sq, 1, 64);
  sq += __shfl_xor(sq, 2, 64);
  float inv = rsqrtf(sq * (1.f / CC) + 1e-5f);
  u16 o[24];
  #pragma unroll
  for (int i = 0; i < 24; ++i) {
    int c = qd * 24 + i;
    o[i] = f2bf((v[i] - mu) * inv * g1[c] + b1[c]);
  }
  *(uint4*)(dst)      = *(const uint4*)(o);
  *(uint4*)(dst + 8)  = *(const uint4*)(o + 8);
  *(uint4*)(dst + 16) = *(const uint4*)(o + 16);
}

// ---------------- K1: per-(window,head) QKV + attention (MFMA) ----------------
__global__ __launch_bounds__(256, 4) void attn_kernel(
    const u16* __restrict__ xnw, const u16* __restrict__ qkv_wT, const float* __restrict__ qkv_b,
    const float* __restrict__ biasT, u16* __restrict__ att)
{
  // union buffer: phases 1-2 -> sQ[112][40] + sK[112][40]; phases 3-4 -> sP[112][136]
  __shared__ __align__(16) u16 sUni[112 * SVP];   // 30464 B
  __shared__ __align__(16) u16 sVt[32 * SVP];     //  8704 B  [d][kv]
  __shared__ int sReg[112];

  u16* sQ = sUni;
  u16* sK = sUni + 112 * SQP;
  u16* sP = sUni;

  const int tid  = threadIdx.x;
  const int bid  = blockIdx.x;
  const int widx = bid / 3;
  const int head = bid - widx * 3;
  const int ww = widx & 15, hw = (widx >> 4) & 15, tw = widx >> 8;
  const bool bnd = (tw == 7) || (hw == 15) || (ww == 15);
  const int wid = tid >> 6;          // wave 0..3
  const int lane = tid & 63;
  const int g  = lane >> 4;          // lane group 0..3
  const int cl = lane & 15;          // col-in-tile

  // ---- phase 0: zero sVt (pad kv cols must be 0) + region ids
  for (int i = tid; i < 32 * SVP / 2; i += 256) ((u32*)sVt)[i] = 0;
  if (tid < 112) {
    int n = tid;
    int reg = 0;
    if (n < NN) {
      int it = n / 49, r = n - it * 49, ih = r / 7, iw = r - ih * 7;
      int ts = tw * 2 + it, hs = hw * 7 + ih, ws2 = ww * 7 + iw;
      int rt = ts < TT - 2 ? 0 : (ts < TT - 1 ? 1 : 2);
      int rh = hs < HH - 7 ? 0 : (hs < HH - 3 ? 1 : 2);
      int rw = ws2 < WD - 7 ? 0 : (ws2 < WD - 3 ? 1 : 2);
      reg = rt * 9 + rh * 3 + rw;
    }
    sReg[n] = reg;
  }
  __syncthreads();

  // ---- phase 1: QKV slice for this head (A-frags straight from global; D -> sQ/sK/sVt)
  {
    const float scale = 0.17677669529663687f;   // 32^-0.5
    #pragma unroll
    for (int mi = 0; mi < 2; ++mi) {
      const int mt = wid + mi * 4;
      if (mt < 7) {
        const u16* arow = xnw + ((size_t)widx * 112 + mt * 16 + cl) * CC + 8 * g;
        bf16x8 a0 = *(const bf16x8*)(arow);
        bf16x8 a1 = *(const bf16x8*)(arow + 32);
        bf16x8 a2 = *(const bf16x8*)(arow + 64);
        #pragma unroll
        for (int nt = 0; nt < 6; ++nt) {
          const int sec = nt >> 1;                      // 0=Q 1=K 2=V
          const int col = sec * 96 + head * 32 + (nt & 1) * 16 + cl;
          const u16* brow = qkv_wT + (size_t)col * CC + 8 * g;
          f32x4 acc = {0.f, 0.f, 0.f, 0.f};
          acc = MFMA16(a0, *(const bf16x8*)(brow), acc);
          acc = MFMA16(a1, *(const bf16x8*)(brow + 32), acc);
          acc = MFMA16(a2, *(const bf16x8*)(brow + 64), acc);
          const float bias = qkv_b[col];
          #pragma unroll
          for (int r = 0; r < 4; ++r) {
            const int row = mt * 16 + 4 * g + r;
            const float v = acc[r] + bias;
            if (sec == 0)      sQ[row * SQP + (nt & 1) * 16 + cl] = f2bf(v * scale);
            else if (sec == 1) sK[row * SQP + (nt & 1) * 16 + cl] = f2bf(v);
            else               sVt[((nt & 1) * 16 + cl) * SVP + row] = f2bf(v);
          }
        }
      }
    }
  }
  __syncthreads();

  // ---- phase 2: QK^T (MFMA, K=32) + bias/mask + in-register softmax
  float sv[2][7][4];
  #pragma unroll
  for (int mi = 0; mi < 2; ++mi) {
    const int mt = wid + mi * 4;
    if (mt >= 7) continue;
    bf16x8 a = *(const bf16x8*)&sQ[(mt * 16 + cl) * SQP + 8 * g];
    #pragma unroll
    for (int nt = 0; nt < 7; ++nt) {
      bf16x8 b = *(const bf16x8*)&sK[(nt * 16 + cl) * SQP + 8 * g];
      f32x4 acc = {0.f, 0.f, 0.f, 0.f};
      acc = MFMA16(a, b, acc);
      #pragma unroll
      for (int r = 0; r < 4; ++r) sv[mi][nt][r] = acc[r];
    }
    const int q0 = mt * 16 + 4 * g;
    #pragma unroll
    for (int nt = 0; nt < 7; ++nt) {
      const int kv = nt * 16 + cl;
      #pragma unroll
      for (int r = 0; r < 4; ++r) {
        const int q = q0 + r;
        float v = sv[mi][nt][r];
        if (kv < NN) {
          if (q < NN) {
            v += biasT[((head * NN + q)) * NN + kv];
            if (bnd && sReg[q] != sReg[kv]) v -= 100.f;
          }
        } else {
          v = -1e30f;
        }
        sv[mi][nt][r] = v;
      }
    }
    #pragma unroll
    for (int r = 0; r < 4; ++r) {
      float mx = sv[mi][0][r];
      #pragma unroll
      for (int nt = 1; nt < 7; ++nt) mx = fmaxf(mx, sv[mi][nt][r]);
      #pragma unroll
      for (int d = 1; d < 16; d <<= 1) mx = fmaxf(mx, __shfl_xor(mx, d, 64));
      float sm = 0.f;
      #pragma unroll
      for (int nt = 0; nt < 7; ++nt) { float p = __expf(sv[mi][nt][r] - mx); sv[mi][nt][r] = p; sm += p; }
      #pragma unroll
      for (int d = 1; d < 16; d <<= 1) sm += __shfl_xor(sm, d, 64);
      const float inv = 1.f / sm;
      #pragma unroll
      for (int nt = 0; nt < 7; ++nt) sv[mi][nt][r] *= inv;
    }
  }
  __syncthreads();   // all Q/K reads complete before P overwrites the union buffer

  // ---- phase 3: write P (bf16) + zero pad cols 112..127
  #pragma unroll
  for (int mi = 0; mi < 2; ++mi) {
    const int mt = wid + mi * 4;
    if (mt >= 7) continue;
    #pragma unroll
    for (int r = 0; r < 4; ++r) {
      const int q = mt * 16 + 4 * g + r;
      u16* prow = &sP[q * SVP];
      #pragma unroll
      for (int nt = 0; nt < 7; ++nt) prow[nt * 16 + cl] = f2bf(sv[mi][nt][r]);
      prow[112 + cl] = 0;
    }
  }
  __syncthreads();

  // ---- phase 4: PV (MFMA, K=128) + store
  for (int t = wid; t < 14; t += 4) {
    const int mt = t >> 1, ntd = t & 1;
    f32x4 acc = {0.f, 0.f, 0.f, 0.f};
    #pragma unroll
    for (int ks = 0; ks < 4; ++ks) {
      bf16x8 a = *(const bf16x8*)&sP[(mt * 16 + cl) * SVP + ks * 32 + 8 * g];
      bf16x8 b = *(const bf16x8*)&sVt[(ntd * 16 + cl) * SVP + ks * 32 + 8 * g];
      acc = MFMA16(a, b, acc);
    }
    #pragma unroll
    for (int r = 0; r < 4; ++r) {
      const int q = mt * 16 + 4 * g + r;
      if (q < NN)
        att[((size_t)widx * NN + q) * CC + head * 32 + ntd * 16 + cl] = f2bf(acc[r]);
    }
  }
}

// ---------------- K2: fused proj + residual + LN2 + FC1 + GELU + FC2 + residual ----------------
// 16 window-tokens per block, 128 threads (2 waves); 4 phases / 3 barriers;
// att A-frags loaded directly from global (contiguous rows) -- no staging phase.
__global__ __launch_bounds__(128, 4) void pm_kernel(
    const u16* __restrict__ att, const u16* __restrict__ proj_wT, const float* __restrict__ proj_b,
    const float* __restrict__ x,
    const float* __restrict__ g2, const float* __restrict__ b2,
    const u16* __restrict__ fc1_wT, const float* __restrict__ fc1_b,
    const u16* __restrict__ fc2_wT, const float* __restrict__ fc2_b,
    float* __restrict__ out)
{
  __shared__ __align__(16) u16 sH [16 * SHP];    // 12544 B
  __shared__ __align__(16) u16 sX1[16 * SX1P];   //  3200 B (bf16 copy of x1 for LN2)
  __shared__ __align__(16) u16 sXn[16 * SXP];    //  3328 B
  // total 19072 B -> 8 blocks/CU (16 waves)

  const int tid  = threadIdx.x;
  const int base = blockIdx.x * 16;              // window-token base
  const int wid = tid >> 6, lane = tid & 63, g = lane >> 4, cl = lane & 15;
  const int hnt = wid;              // nt-range half (0..1)

  // ---- P-1: natural-row indices + EARLY x-residual prefetch (hides under P1)
  u32 nr[4];
  #pragma unroll
  for (int r = 0; r < 4; ++r) {
    int tok = base + 4 * g + r;
    int widx = tok / NN, n = tok - widx * NN;
    int ww = widx & 15, hw = (widx >> 4) & 15, tw = widx >> 8;
    int it = n / 49, rr = n - it * 49, ih = rr / 7, iw = rr - ih * 7;
    int t = tw * 2 + it + 1; if (t >= TT) t -= TT;
    int h = hw * 7 + ih + 3; if (h >= HH) h -= HH;
    int w = ww * 7 + iw + 3; if (w >= WD) w -= WD;
    nr[r] = (u32)((t * HH + h) * WD + w);
  }
  float xres[3][4];
  #pragma unroll
  for (int j = 0; j < 3; ++j) {
    const int col = (hnt * 3 + j) * 16 + cl;
    #pragma unroll
    for (int r = 0; r < 4; ++r)
      xres[j][r] = x[(size_t)nr[r] * CC + col];
  }

  // ---- P1: proj GEMM [16x96]@[96x96] + x residual -> x1 regs + sX1 (bf16)
  // A-frags direct from global att (rows contiguous, 16B aligned)
  float x1v[3][4];
  {
    const u16* aRow = att + (size_t)(base + cl) * CC + 8 * g;
    bf16x8 a0 = *(const bf16x8*)(aRow);
    bf16x8 a1 = *(const bf16x8*)(aRow + 32);
    bf16x8 a2 = *(const bf16x8*)(aRow + 64);
    #pragma unroll
    for (int j = 0; j < 3; ++j) {
      const int nt = hnt * 3 + j;
      const u16* bRow = proj_wT + (nt * 16 + cl) * CC + 8 * g;
      f32x4 acc = {0.f, 0.f, 0.f, 0.f};
      acc = MFMA16(a0, *(const bf16x8*)(bRow), acc);
      acc = MFMA16(a1, *(const bf16x8*)(bRow + 32), acc);
      acc = MFMA16(a2, *(const bf16x8*)(bRow + 64), acc);
      const float bc = proj_b[nt * 16 + cl];
      #pragma unroll
      for (int r = 0; r < 4; ++r) {
        const int row = 4 * g + r;
        const float v = acc[r] + bc + xres[j][r];
        x1v[j][r] = v;
        sX1[row * SX1P + nt * 16 + cl] = f2bf(v);
      }
    }
  }
  __syncthreads();

  // ---- P2: LN2 from sX1 (bf16): token = tid>>3 (16), sub = tid&7 (12 ch); 8-lane shfl reduce
  {
    const int tok = tid >> 3, sub = tid & 7;
    const u16* p = &sX1[tok * SX1P + sub * 12];
    float v[12];
    #pragma unroll
    for (int k = 0; k < 6; ++k) {
      u32 u = *(const u32*)(p + 2 * k);
      v[2 * k] = bflo(u); v[2 * k + 1] = bfhi(u);
    }
    float sm = 0.f;
    #pragma unroll
    for (int i = 0; i < 12; ++i) sm += v[i];
    sm += __shfl_xor(sm, 1, 64);
    sm += __shfl_xor(sm, 2, 64);
    sm += __shfl_xor(sm, 4, 64);
    float mu = sm * (1.f / CC);
    float sq = 0.f;
    #pragma unroll
    for (int i = 0; i < 12; ++i) { float d = v[i] - mu; sq += d * d; }
    sq += __shfl_xor(sq, 1, 64);
    sq += __shfl_xor(sq, 2, 64);
    sq += __shfl_xor(sq, 4, 64);
    float inv = rsqrtf(sq * (1.f / CC) + 1e-5f);
    u16 o[12];
    #pragma unroll
    for (int i = 0; i < 12; ++i) {
      int c = sub * 12 + i;
      o[i] = f2bf((v[i] - mu) * inv * g2[c] + b2[c]);
    }
    u16* dst = &sXn[tok * SXP + sub * 12];
    *(uint2*)(dst)     = *(const uint2*)(o);
    *(uint2*)(dst + 4) = *(const uint2*)(o + 4);
    *(uint2*)(dst + 8) = *(const uint2*)(o + 8);
  }
  __syncthreads();

  // ---- P3: FC1 [16x96]@[96x384] + GELU -> sH (wave does nts [hnt*12, +12))
  {
    const u16* aXn = &sXn[cl * SXP + 8 * g];
    bf16x8 xa0 = *(const bf16x8*)(aXn);
    bf16x8 xa1 = *(const bf16x8*)(aXn + 32);
    bf16x8 xa2 = *(const bf16x8*)(aXn + 64);
    const int nt0 = hnt * 12;
    const u16* bPtr = fc1_wT + ((size_t)(nt0 * 16 + cl)) * CC + 8 * g;
    bf16x8 b0 = *(const bf16x8*)(bPtr);
    bf16x8 b1 = *(const bf16x8*)(bPtr + 32);
    bf16x8 b2 = *(const bf16x8*)(bPtr + 64);
    #pragma unroll
    for (int j = 0; j < 12; ++j) {
      bf16x8 c0 = b0, c1 = b1, c2 = b2;
      if (j < 11) {                       // prefetch next nt
        bPtr += 16 * CC;
        b0 = *(const bf16x8*)(bPtr);
        b1 = *(const bf16x8*)(bPtr + 32);
        b2 = *(const bf16x8*)(bPtr + 64);
      }
      f32x4 acc = {0.f, 0.f, 0.f, 0.f};
      acc = MFMA16(xa0, c0, acc);
      acc = MFMA16(xa1, c1, acc);
      acc = MFMA16(xa2, c2, acc);
      const int nt = nt0 + j;
      const float bj = fc1_b[nt * 16 + cl];
      #pragma unroll
      for (int r = 0; r < 4; ++r) {
        float v = acc[r] + bj;
        // tanh-GELU: v*e/(e+1), e = exp(v*(1.59576912 + 0.07135481*v^2))
        float p2 = v * v;
        float a  = v * fmaf(0.07135481f, p2, 1.59576912f);
        float e  = __expf(a);
        float gl = v * e * __builtin_amdgcn_rcpf(e + 1.f);
        sH[(4 * g + r) * SHP + nt * 16 + cl] = f2bf(gl);
      }
    }
  }
  __syncthreads();

  // ---- P4: FC2 [16x384]@[384x96] (two 6-frag k-halves) + epilogue
  {
    f32x4 acc2[3];
    #pragma unroll
    for (int j = 0; j < 3; ++j) { f32x4 z = {0.f, 0.f, 0.f, 0.f}; acc2[j] = z; }
    #pragma unroll
    for (int half = 0; half < 2; ++half) {
      const u16* aBase = &sH[cl * SHP + half * 192 + 8 * g];
      bf16x8 a[6];
      #pragma unroll
      for (int ks = 0; ks < 6; ++ks) a[ks] = *(const bf16x8*)(aBase + 32 * ks);
      #pragma unroll
      for (int j = 0; j < 3; ++j) {
        const int nt = hnt * 3 + j;
        const u16* bBase = fc2_wT + (size_t)(nt * 16 + cl) * MLPH + half * 192 + 8 * g;
        #pragma unroll
        for (int ks = 0; ks < 6; ++ks)
          acc2[j] = MFMA16(a[ks], *(const bf16x8*)(bBase + 32 * ks), acc2[j]);
      }
    }
    #pragma unroll
    for (int j = 0; j < 3; ++j) {
      const int nt = hnt * 3 + j;
      const float bc = fc2_b[nt * 16 + cl];
      #pragma unroll
      for (int r = 0; r < 4; ++r) {
        out[(size_t)nr[r] * CC + nt * 16 + cl] = x1v[j][r] + acc2[j][r] + bc;
      }
    }
  }
}

extern "C" void kernel_launch(void* const* d_in, const int* in_sizes, int n_in,
                              void* d_out, int out_size, void* d_ws, size_t ws_size,
                              hipStream_t stream) {
  const float* x      = (const float*)d_in[0];
  const float* g1     = (const float*)d_in[1];
  const float* b1     = (const float*)d_in[2];
  const float* qkv_w  = (const float*)d_in[3];
  const float* qkv_b  = (const float*)d_in[4];
  const float* rpb    = (const float*)d_in[5];
  const float* proj_w = (const float*)d_in[6];
  const float* proj_b = (const float*)d_in[7];
  const float* g2     = (const float*)d_in[8];
  const float* b2     = (const float*)d_in[9];
  const float* fc1_w  = (const float*)d_in[10];
  const float* fc1_b  = (const float*)d_in[11];
  const float* fc2_w  = (const float*)d_in[12];
  const float* fc2_b  = (const float*)d_in[13];

  char* ws = (char*)d_ws;
  u16*   att    = (u16*)ws;                                   // NTOK*96 bf16 = 38.5 MB
  u16*   xnw    = (u16*)(ws + (size_t)NTOK * CC * 2);         // NWIN*112*96 bf16 = 44 MB
  char*  wtail  = ws + (size_t)NTOK * CC * 2 + (size_t)NWIN * 112 * CC * 2;
  float* biasT  = (float*)wtail;                              // 115248 B
  u16*   qkv_wT = (u16*)(wtail + 115248);                     // 55296 B
  u16*   proj_wT= (u16*)(wtail + 115248 + 55296);             // 18432 B
  u16*   fc1_wT = (u16*)(wtail + 115248 + 55296 + 18432);     // 73728 B
  u16*   fc2_wT = (u16*)(wtail + 115248 + 55296 + 18432 + 73728); // 73728 B

  wprep_kernel<<<(27648 + 9216 + 36864 + 36864 + 255) / 256, 256, 0, stream>>>(
      qkv_w, proj_w, fc1_w, fc2_w, qkv_wT, proj_wT, fc1_wT, fc2_wT);
  bias_kernel<<<(NHEADS * NN * NN + 255) / 256, 256, 0, stream>>>(rpb, biasT);
  ln1_kernel<<<NWIN * 112 / 64, 256, 0, stream>>>(x, g1, b1, xnw);
  attn_kernel<<<NWIN * NHEADS, 256, 0, stream>>>(xnw, qkv_wT, qkv_b, biasT, att);
  pm_kernel<<<NTOK / 16, 128, 0, stream>>>(att, proj_wT, proj_b, x, g2, b2,
                                           fc1_wT, fc1_b, fc2_wT, fc2_b, (float*)d_out);
}

// Round 12
// 357.252 us; speedup vs baseline: 1.0053x; 1.0053x over previous
//
#include <hip/hip_runtime.h>
#include <math.h>

#define TT 16
#define HH 112
#define WD 112
#define CC 96
#define NHEADS 3
#define HD 32
#define NN 98          // window tokens 2*7*7
#define NWIN 2048      // 8*16*16
#define NTOK 200704    // T*H*W == NWIN*NN
#define MLPH 384
#define SXP 104        // row stride (bf16) LDS tiles (208B rows, 16B aligned)
#define SQP 40         // row stride (bf16) per-head sQ/sK
#define SVP 136        // row stride (bf16) sVt/sP
#define SH2P 200       // row stride (bf16) sH half (192 cols + 8 pad)

typedef unsigned int  u32;
typedef unsigned short u16;
typedef float f32x4 __attribute__((ext_vector_type(4)));
typedef short bf16x8 __attribute__((ext_vector_type(8)));

__device__ inline u16 f2bf(float f) {
  u32 u = __float_as_uint(f);
  u += 0x7fffu + ((u >> 16) & 1u);
  return (u16)(u >> 16);
}
__device__ inline float bflo(u32 u) { return __uint_as_float(u << 16); }
__device__ inline float bfhi(u32 u) { return __uint_as_float(u & 0xffff0000u); }

#define MFMA16(a, b, c) __builtin_amdgcn_mfma_f32_16x16x32_bf16((a), (b), (c), 0, 0, 0)

// ---------------- K0a: transpose all weights to bf16 col-major ----------------
__global__ __launch_bounds__(256) void wprep_kernel(
    const float* __restrict__ qkv_w, const float* __restrict__ proj_w,
    const float* __restrict__ fc1_w, const float* __restrict__ fc2_w,
    u16* __restrict__ qkv_wT, u16* __restrict__ proj_wT,
    u16* __restrict__ fc1_wT, u16* __restrict__ fc2_wT) {
  int idx = blockIdx.x * 256 + threadIdx.x;
  if (idx < 27648) {                       // qkv_wT[col][c]
    int col = idx / CC, c = idx - col * CC;
    qkv_wT[idx] = f2bf(qkv_w[c * (3 * CC) + col]);
    return;
  }
  idx -= 27648;
  if (idx < 9216) {                        // proj_wT[col][c]
    int col = idx / CC, c = idx - col * CC;
    proj_wT[idx] = f2bf(proj_w[c * CC + col]);
    return;
  }
  idx -= 9216;
  if (idx < 36864) {                       // fc1_wT[j][c]
    int j = idx / CC, c = idx - j * CC;
    fc1_wT[idx] = f2bf(fc1_w[c * MLPH + j]);
    return;
  }
  idx -= 36864;
  if (idx < 36864) {                       // fc2_wT[c][j]
    int c = idx / MLPH, j = idx - c * MLPH;
    fc2_wT[idx] = f2bf(fc2_w[j * CC + c]);
  }
}

// ---------------- K0b: biasT[head][q][kv] = rpb[ridx(q,kv)*3+head] ----------------
__global__ __launch_bounds__(256) void bias_kernel(const float* __restrict__ rpb,
                                                   float* __restrict__ biasT) {
  int idx = blockIdx.x * 256 + threadIdx.x;
  if (idx >= NHEADS * NN * NN) return;
  int head = idx / (NN * NN);
  int r = idx - head * NN * NN;
  int q = r / NN, kv = r - q * NN;
  int itq = q / 49, rq = q - itq * 49, ihq = rq / 7, iwq = rq - ihq * 7;
  int itk = kv / 49, rk = kv - itk * 49, ihk = rk / 7, iwk = rk - ihk * 7;
  int ridx = (itq - itk + 1) * 169 + (ihq - ihk + 6) * 13 + (iwq - iwk + 6);
  biasT[idx] = rpb[ridx * NHEADS + head];
}

// ---------------- K0c: LN1 + shift-roll + window gather -> xnw[widx][112][96] bf16 ----------------
__global__ __launch_bounds__(256) void ln1_kernel(
    const float* __restrict__ x, const float* __restrict__ g1, const float* __restrict__ b1,
    u16* __restrict__ xnw)
{
  const int tid = threadIdx.x;
  const int row = blockIdx.x * 64 + (tid >> 2);   // 0 .. NWIN*112-1
  const int qd = tid & 3;                          // quarter: 24 channels
  const int widx = row / 112;
  const int n = row - widx * 112;
  u16* dst = xnw + (size_t)row * CC + qd * 24;
  if (n >= NN) {                                   // pad row -> zeros
    uint4 z = {0u, 0u, 0u, 0u};
    *(uint4*)(dst) = z; *(uint4*)(dst + 8) = z; *(uint4*)(dst + 16) = z;
    return;
  }
  int it = n / 49, r = n - it * 49, ih = r / 7, iw = r - ih * 7;
  int ww = widx & 15, hw = (widx >> 4) & 15, tw = widx >> 8;
  int t = tw * 2 + it + 1; if (t >= TT) t -= TT;
  int h = hw * 7 + ih + 3; if (h >= HH) h -= HH;
  int w = ww * 7 + iw + 3; if (w >= WD) w -= WD;
  const float* src = x + ((size_t)(t * HH + h) * WD + w) * CC + qd * 24;
  float v[24];
  #pragma unroll
  for (int i = 0; i < 24; i += 4) {
    float4 f = *(const float4*)(src + i);
    v[i] = f.x; v[i + 1] = f.y; v[i + 2] = f.z; v[i + 3] = f.w;
  }
  float sm = 0.f;
  #pragma unroll
  for (int i = 0; i < 24; ++i) sm += v[i];
  sm += __shfl_xor(sm, 1, 64);
  sm += __shfl_xor(sm, 2, 64);
  float mu = sm * (1.f / CC);
  float sq = 0.f;
  #pragma unroll
  for (int i = 0; i < 24; ++i) { float d = v[i] - mu; sq += d * d; }
  sq += __shfl_xor(sq, 1, 64);
  sq += __shfl_xor(sq, 2, 64);
  float inv = rsqrtf(sq * (1.f / CC) + 1e-5f);
  u16 o[24];
  #pragma unroll
  for (int i = 0; i < 24; ++i) {
    int c = qd * 24 + i;
    o[i] = f2bf((v[i] - mu) * inv * g1[c] + b1[c]);
  }
  *(uint4*)(dst)      = *(const uint4*)(o);
  *(uint4*)(dst + 8)  = *(const uint4*)(o + 8);
  *(uint4*)(dst + 16) = *(const uint4*)(o + 16);
}

// ---------------- K1: per-(window,head) QKV + attention (MFMA) ----------------
__global__ __launch_bounds__(256, 4) void attn_kernel(
    const u16* __restrict__ xnw, const u16* __restrict__ qkv_wT, const float* __restrict__ qkv_b,
    const float* __restrict__ biasT, u16* __restrict__ att)
{
  // union buffer: phases 1-2 -> sQ[112][40] + sK[112][40]; phases 3-4 -> sP[112][136]
  __shared__ __align__(16) u16 sUni[112 * SVP];   // 30464 B
  __shared__ __align__(16) u16 sVt[32 * SVP];     //  8704 B  [d][kv]
  __shared__ int sReg[112];

  u16* sQ = sUni;
  u16* sK = sUni + 112 * SQP;
  u16* sP = sUni;

  const int tid  = threadIdx.x;
  const int bid  = blockIdx.x;
  const int widx = bid / 3;
  const int head = bid - widx * 3;
  const int ww = widx & 15, hw = (widx >> 4) & 15, tw = widx >> 8;
  const bool bnd = (tw == 7) || (hw == 15) || (ww == 15);
  const int wid = tid >> 6;          // wave 0..3
  const int lane = tid & 63;
  const int g  = lane >> 4;          // lane group 0..3
  const int cl = lane & 15;          // col-in-tile

  // ---- phase 0: zero sVt (pad kv cols must be 0) + region ids
  for (int i = tid; i < 32 * SVP / 2; i += 256) ((u32*)sVt)[i] = 0;
  if (tid < 112) {
    int n = tid;
    int reg = 0;
    if (n < NN) {
      int it = n / 49, r = n - it * 49, ih = r / 7, iw = r - ih * 7;
      int ts = tw * 2 + it, hs = hw * 7 + ih, ws2 = ww * 7 + iw;
      int rt = ts < TT - 2 ? 0 : (ts < TT - 1 ? 1 : 2);
      int rh = hs < HH - 7 ? 0 : (hs < HH - 3 ? 1 : 2);
      int rw = ws2 < WD - 7 ? 0 : (ws2 < WD - 3 ? 1 : 2);
      reg = rt * 9 + rh * 3 + rw;
    }
    sReg[n] = reg;
  }
  __syncthreads();

  // ---- phase 1: QKV slice for this head (A-frags straight from global; D -> sQ/sK/sVt)
  {
    const float scale = 0.17677669529663687f;   // 32^-0.5
    #pragma unroll
    for (int mi = 0; mi < 2; ++mi) {
      const int mt = wid + mi * 4;
      if (mt < 7) {
        const u16* arow = xnw + ((size_t)widx * 112 + mt * 16 + cl) * CC + 8 * g;
        bf16x8 a0 = *(const bf16x8*)(arow);
        bf16x8 a1 = *(const bf16x8*)(arow + 32);
        bf16x8 a2 = *(const bf16x8*)(arow + 64);
        #pragma unroll
        for (int nt = 0; nt < 6; ++nt) {
          const int sec = nt >> 1;                      // 0=Q 1=K 2=V
          const int col = sec * 96 + head * 32 + (nt & 1) * 16 + cl;
          const u16* brow = qkv_wT + (size_t)col * CC + 8 * g;
          f32x4 acc = {0.f, 0.f, 0.f, 0.f};
          acc = MFMA16(a0, *(const bf16x8*)(brow), acc);
          acc = MFMA16(a1, *(const bf16x8*)(brow + 32), acc);
          acc = MFMA16(a2, *(const bf16x8*)(brow + 64), acc);
          const float bias = qkv_b[col];
          #pragma unroll
          for (int r = 0; r < 4; ++r) {
            const int row = mt * 16 + 4 * g + r;
            const float v = acc[r] + bias;
            if (sec == 0)      sQ[row * SQP + (nt & 1) * 16 + cl] = f2bf(v * scale);
            else if (sec == 1) sK[row * SQP + (nt & 1) * 16 + cl] = f2bf(v);
            else               sVt[((nt & 1) * 16 + cl) * SVP + row] = f2bf(v);
          }
        }
      }
    }
  }
  __syncthreads();

  // ---- phase 2: QK^T (MFMA, K=32) + bias/mask + in-register softmax
  float sv[2][7][4];
  #pragma unroll
  for (int mi = 0; mi < 2; ++mi) {
    const int mt = wid + mi * 4;
    if (mt >= 7) continue;
    bf16x8 a = *(const bf16x8*)&sQ[(mt * 16 + cl) * SQP + 8 * g];
    #pragma unroll
    for (int nt = 0; nt < 7; ++nt) {
      bf16x8 b = *(const bf16x8*)&sK[(nt * 16 + cl) * SQP + 8 * g];
      f32x4 acc = {0.f, 0.f, 0.f, 0.f};
      acc = MFMA16(a, b, acc);
      #pragma unroll
      for (int r = 0; r < 4; ++r) sv[mi][nt][r] = acc[r];
    }
    const int q0 = mt * 16 + 4 * g;
    #pragma unroll
    for (int nt = 0; nt < 7; ++nt) {
      const int kv = nt * 16 + cl;
      #pragma unroll
      for (int r = 0; r < 4; ++r) {
        const int q = q0 + r;
        float v = sv[mi][nt][r];
        if (kv < NN) {
          if (q < NN) {
            v += biasT[((head * NN + q)) * NN + kv];
            if (bnd && sReg[q] != sReg[kv]) v -= 100.f;
          }
        } else {
          v = -1e30f;
        }
        sv[mi][nt][r] = v;
      }
    }
    #pragma unroll
    for (int r = 0; r < 4; ++r) {
      float mx = sv[mi][0][r];
      #pragma unroll
      for (int nt = 1; nt < 7; ++nt) mx = fmaxf(mx, sv[mi][nt][r]);
      #pragma unroll
      for (int d = 1; d < 16; d <<= 1) mx = fmaxf(mx, __shfl_xor(mx, d, 64));
      float sm = 0.f;
      #pragma unroll
      for (int nt = 0; nt < 7; ++nt) { float p = __expf(sv[mi][nt][r] - mx); sv[mi][nt][r] = p; sm += p; }
      #pragma unroll
      for (int d = 1; d < 16; d <<= 1) sm += __shfl_xor(sm, d, 64);
      const float inv = 1.f / sm;
      #pragma unroll
      for (int nt = 0; nt < 7; ++nt) sv[mi][nt][r] *= inv;
    }
  }
  __syncthreads();   // all Q/K reads complete before P overwrites the union buffer

  // ---- phase 3: write P (bf16) + zero pad cols 112..127
  #pragma unroll
  for (int mi = 0; mi < 2; ++mi) {
    const int mt = wid + mi * 4;
    if (mt >= 7) continue;
    #pragma unroll
    for (int r = 0; r < 4; ++r) {
      const int q = mt * 16 + 4 * g + r;
      u16* prow = &sP[q * SVP];
      #pragma unroll
      for (int nt = 0; nt < 7; ++nt) prow[nt * 16 + cl] = f2bf(sv[mi][nt][r]);
      prow[112 + cl] = 0;
    }
  }
  __syncthreads();

  // ---- phase 4: PV (MFMA, K=128) + store
  for (int t = wid; t < 14; t += 4) {
    const int mt = t >> 1, ntd = t & 1;
    f32x4 acc = {0.f, 0.f, 0.f, 0.f};
    #pragma unroll
    for (int ks = 0; ks < 4; ++ks) {
      bf16x8 a = *(const bf16x8*)&sP[(mt * 16 + cl) * SVP + ks * 32 + 8 * g];
      bf16x8 b = *(const bf16x8*)&sVt[(ntd * 16 + cl) * SVP + ks * 32 + 8 * g];
      acc = MFMA16(a, b, acc);
    }
    #pragma unroll
    for (int r = 0; r < 4; ++r) {
      const int q = mt * 16 + 4 * g + r;
      if (q < NN)
        att[((size_t)widx * NN + q) * CC + head * 32 + ntd * 16 + cl] = f2bf(acc[r]);
    }
  }
}

// ---------------- K2: fused proj + residual + LN2 + FC1 + GELU + FC2 + residual ----------------
// WAVE-LOCAL: each wave owns a 16-token tile end-to-end. ZERO __syncthreads.
// LN2 fully in registers (shfl over the 16-lane cl-group). Per-wave private LDS
// used only for the two k-transposes (xn -> FC1 A, H-half -> FC2 A).
__global__ __launch_bounds__(128, 3) void pm_kernel(
    const u16* __restrict__ att, const u16* __restrict__ proj_wT, const float* __restrict__ proj_b,
    const float* __restrict__ x,
    const float* __restrict__ g2, const float* __restrict__ b2,
    const u16* __restrict__ fc1_wT, const float* __restrict__ fc1_b,
    const u16* __restrict__ fc2_wT, const float* __restrict__ fc2_b,
    float* __restrict__ out)
{
  __shared__ __align__(16) u16 sXn[2][16 * SXP];    // 2 x 3328 B (per-wave)
  __shared__ __align__(16) u16 sHh[2][16 * SH2P];   // 2 x 6400 B (per-wave half-H)
  // total 19456 B -> 8 blocks/CU by LDS

  const int tid  = threadIdx.x;
  const int wid  = tid >> 6, lane = tid & 63, g = lane >> 4, cl = lane & 15;
  const int tile = blockIdx.x * 2 + wid;         // 16-token tile
  const int base = tile * 16;

  u16* mXn = sXn[wid];
  u16* mHh = sHh[wid];

  // ---- natural-row indices + x-residual init (x1v starts as the residual)
  u32 nr[4];
  #pragma unroll
  for (int r = 0; r < 4; ++r) {
    int tok = base + 4 * g + r;
    int widx = tok / NN, n = tok - widx * NN;
    int ww = widx & 15, hw = (widx >> 4) & 15, tw = widx >> 8;
    int it = n / 49, rr = n - it * 49, ih = rr / 7, iw = rr - ih * 7;
    int t = tw * 2 + it + 1; if (t >= TT) t -= TT;
    int h = hw * 7 + ih + 3; if (h >= HH) h -= HH;
    int w = ww * 7 + iw + 3; if (w >= WD) w -= WD;
    nr[r] = (u32)((t * HH + h) * WD + w);
  }
  float x1v[6][4];
  #pragma unroll
  for (int nt = 0; nt < 6; ++nt) {
    const int col = nt * 16 + cl;
    #pragma unroll
    for (int r = 0; r < 4; ++r)
      x1v[nt][r] = x[(size_t)nr[r] * CC + col];
  }

  // ---- P1: proj GEMM [16x96]@[96x96]; A direct from global att; += into x1v
  {
    const u16* aRow = att + (size_t)(base + cl) * CC + 8 * g;
    bf16x8 a0 = *(const bf16x8*)(aRow);
    bf16x8 a1 = *(const bf16x8*)(aRow + 32);
    bf16x8 a2 = *(const bf16x8*)(aRow + 64);
    #pragma unroll
    for (int nt = 0; nt < 6; ++nt) {
      const u16* bRow = proj_wT + (nt * 16 + cl) * CC + 8 * g;
      f32x4 acc = {0.f, 0.f, 0.f, 0.f};
      acc = MFMA16(a0, *(const bf16x8*)(bRow), acc);
      acc = MFMA16(a1, *(const bf16x8*)(bRow + 32), acc);
      acc = MFMA16(a2, *(const bf16x8*)(bRow + 64), acc);
      const float bc = proj_b[nt * 16 + cl];
      #pragma unroll
      for (int r = 0; r < 4; ++r)
        x1v[nt][r] += acc[r] + bc;
    }
  }

  // ---- P2: LN2 fully in registers; write xn (bf16) to per-wave LDS for FC1-A transpose
  {
    float g2v[6], b2v[6];
    #pragma unroll
    for (int nt = 0; nt < 6; ++nt) {
      g2v[nt] = g2[nt * 16 + cl];
      b2v[nt] = b2[nt * 16 + cl];
    }
    #pragma unroll
    for (int r = 0; r < 4; ++r) {
      float sm = 0.f;
      #pragma unroll
      for (int nt = 0; nt < 6; ++nt) sm += x1v[nt][r];
      sm += __shfl_xor(sm, 1, 64);
      sm += __shfl_xor(sm, 2, 64);
      sm += __shfl_xor(sm, 4, 64);
      sm += __shfl_xor(sm, 8, 64);
      const float mu = sm * (1.f / CC);
      float sq = 0.f;
      #pragma unroll
      for (int nt = 0; nt < 6; ++nt) { float d = x1v[nt][r] - mu; sq += d * d; }
      sq += __shfl_xor(sq, 1, 64);
      sq += __shfl_xor(sq, 2, 64);
      sq += __shfl_xor(sq, 4, 64);
      sq += __shfl_xor(sq, 8, 64);
      const float inv = rsqrtf(sq * (1.f / CC) + 1e-5f);
      #pragma unroll
      for (int nt = 0; nt < 6; ++nt)
        mXn[(4 * g + r) * SXP + nt * 16 + cl] =
            f2bf((x1v[nt][r] - mu) * inv * g2v[nt] + b2v[nt]);
    }
  }
  // same-wave LDS write->read dependency: compiler inserts lgkmcnt; DS ops per-wave in order

  // ---- P3/P4: FC1(+GELU) and FC2 in two 192-col halves through per-wave sHh
  f32x4 acc2[6];
  #pragma unroll
  for (int nt = 0; nt < 6; ++nt) { f32x4 z = {0.f, 0.f, 0.f, 0.f}; acc2[nt] = z; }

  const u16* aXn = &mXn[cl * SXP + 8 * g];
  bf16x8 xa0 = *(const bf16x8*)(aXn);
  bf16x8 xa1 = *(const bf16x8*)(aXn + 32);
  bf16x8 xa2 = *(const bf16x8*)(aXn + 64);

  #pragma unroll
  for (int half = 0; half < 2; ++half) {
    // FC1 half: 12 nt, B prefetched 1 ahead
    {
      const int nt0 = half * 12;
      const u16* bPtr = fc1_wT + ((size_t)(nt0 * 16 + cl)) * CC + 8 * g;
      bf16x8 b0 = *(const bf16x8*)(bPtr);
      bf16x8 b1 = *(const bf16x8*)(bPtr + 32);
      bf16x8 b2 = *(const bf16x8*)(bPtr + 64);
      #pragma unroll
      for (int j = 0; j < 12; ++j) {
        bf16x8 c0 = b0, c1 = b1, c2 = b2;
        if (j < 11) {
          bPtr += 16 * CC;
          b0 = *(const bf16x8*)(bPtr);
          b1 = *(const bf16x8*)(bPtr + 32);
          b2 = *(const bf16x8*)(bPtr + 64);
        }
        f32x4 acc = {0.f, 0.f, 0.f, 0.f};
        acc = MFMA16(xa0, c0, acc);
        acc = MFMA16(xa1, c1, acc);
        acc = MFMA16(xa2, c2, acc);
        const int nt = nt0 + j;
        const float bj = fc1_b[nt * 16 + cl];
        #pragma unroll
        for (int r = 0; r < 4; ++r) {
          float v = acc[r] + bj;
          // tanh-GELU: v*e/(e+1), e = exp(v*(1.59576912 + 0.07135481*v^2))
          float p2 = v * v;
          float a  = v * fmaf(0.07135481f, p2, 1.59576912f);
          float e  = __expf(a);
          float gl = v * e * __builtin_amdgcn_rcpf(e + 1.f);
          mHh[(4 * g + r) * SH2P + j * 16 + cl] = f2bf(gl);
        }
      }
    }
    // FC2 partial (k-slice half*192..+192); same-wave LDS ordering guards sHh reuse
    {
      const u16* aBase = &mHh[cl * SH2P + 8 * g];
      bf16x8 a[6];
      #pragma unroll
      for (int ks = 0; ks < 6; ++ks) a[ks] = *(const bf16x8*)(aBase + 32 * ks);
      #pragma unroll
      for (int nt = 0; nt < 6; ++nt) {
        const u16* bBase = fc2_wT + (size_t)(nt * 16 + cl) * MLPH + half * 192 + 8 * g;
        #pragma unroll
        for (int ks = 0; ks < 6; ++ks)
          acc2[nt] = MFMA16(a[ks], *(const bf16x8*)(bBase + 32 * ks), acc2[nt]);
      }
    }
  }

  // ---- epilogue: out = x1(reg) + fc2_b + acc2
  #pragma unroll
  for (int nt = 0; nt < 6; ++nt) {
    const float bc = fc2_b[nt * 16 + cl];
    #pragma unroll
    for (int r = 0; r < 4; ++r)
      out[(size_t)nr[r] * CC + nt * 16 + cl] = x1v[nt][r] + acc2[nt][r] + bc;
  }
}

extern "C" void kernel_launch(void* const* d_in, const int* in_sizes, int n_in,
                              void* d_out, int out_size, void* d_ws, size_t ws_size,
                              hipStream_t stream) {
  const float* x      = (const float*)d_in[0];
  const float* g1     = (const float*)d_in[1];
  const float* b1     = (const float*)d_in[2];
  const float* qkv_w  = (const float*)d_in[3];
  const float* qkv_b  = (const float*)d_in[4];
  const float* rpb    = (const float*)d_in[5];
  const float* proj_w = (const float*)d_in[6];
  const float* proj_b = (const float*)d_in[7];
  const float* g2     = (const float*)d_in[8];
  const float* b2     = (const float*)d_in[9];
  const float* fc1_w  = (const float*)d_in[10];
  const float* fc1_b  = (const float*)d_in[11];
  const float* fc2_w  = (const float*)d_in[12];
  const float* fc2_b  = (const float*)d_in[13];

  char* ws = (char*)d_ws;
  u16*   att    = (u16*)ws;                                   // NTOK*96 bf16 = 38.5 MB
  u16*   xnw    = (u16*)(ws + (size_t)NTOK * CC * 2);         // NWIN*112*96 bf16 = 44 MB
  char*  wtail  = ws + (size_t)NTOK * CC * 2 + (size_t)NWIN * 112 * CC * 2;
  float* biasT  = (float*)wtail;                              // 115248 B
  u16*   qkv_wT = (u16*)(wtail + 115248);                     // 55296 B
  u16*   proj_wT= (u16*)(wtail + 115248 + 55296);             // 18432 B
  u16*   fc1_wT = (u16*)(wtail + 115248 + 55296 + 18432);     // 73728 B
  u16*   fc2_wT = (u16*)(wtail + 115248 + 55296 + 18432 + 73728); // 73728 B

  wprep_kernel<<<(27648 + 9216 + 36864 + 36864 + 255) / 256, 256, 0, stream>>>(
      qkv_w, proj_w, fc1_w, fc2_w, qkv_wT, proj_wT, fc1_wT, fc2_wT);
  bias_kernel<<<(NHEADS * NN * NN + 255) / 256, 256, 0, stream>>>(rpb, biasT);
  ln1_kernel<<<NWIN * 112 / 64, 256, 0, stream>>>(x, g1, b1, xnw);
  attn_kernel<<<NWIN * NHEADS, 256, 0, stream>>>(xnw, qkv_wT, qkv_b, biasT, att);
  pm_kernel<<<NTOK / 32, 128, 0, stream>>>(att, proj_wT, proj_b, x, g2, b2,
                                           fc1_wT, fc1_b, fc2_wT, fc2_b, (float*)d_out);
}

// Round 13
// 355.226 us; speedup vs baseline: 1.0110x; 1.0057x over previous
//
#include <hip/hip_runtime.h>
#include <math.h>

#define TT 16
#define HH 112
#define WD 112
#define CC 96
#define NHEADS 3
#define HD 32
#define NN 98          // window tokens 2*7*7
#define NWIN 2048      // 8*16*16
#define NTOK 200704    // T*H*W == NWIN*NN
#define MLPH 384
#define SXP 104        // row stride (bf16) LDS tiles (208B rows, 16B aligned)
#define SQP 40         // row stride (bf16) per-head sQ/sK
#define SVP 136        // row stride (bf16) sVt/sP
#define SHP 392        // row stride (bf16) sH full (384 cols + 8 pad)
#define SX1P 100       // row stride (bf16) sX1

typedef unsigned int  u32;
typedef unsigned short u16;
typedef float f32x4 __attribute__((ext_vector_type(4)));
typedef short bf16x8 __attribute__((ext_vector_type(8)));

__device__ inline u16 f2bf(float f) {
  u32 u = __float_as_uint(f);
  u += 0x7fffu + ((u >> 16) & 1u);
  return (u16)(u >> 16);
}
__device__ inline float bflo(u32 u) { return __uint_as_float(u << 16); }
__device__ inline float bfhi(u32 u) { return __uint_as_float(u & 0xffff0000u); }

#define MFMA16(a, b, c) __builtin_amdgcn_mfma_f32_16x16x32_bf16((a), (b), (c), 0, 0, 0)

// ---------------- K0a: transpose all weights to bf16 col-major ----------------
__global__ __launch_bounds__(256) void wprep_kernel(
    const float* __restrict__ qkv_w, const float* __restrict__ proj_w,
    const float* __restrict__ fc1_w, const float* __restrict__ fc2_w,
    u16* __restrict__ qkv_wT, u16* __restrict__ proj_wT,
    u16* __restrict__ fc1_wT, u16* __restrict__ fc2_wT) {
  int idx = blockIdx.x * 256 + threadIdx.x;
  if (idx < 27648) {                       // qkv_wT[col][c]
    int col = idx / CC, c = idx - col * CC;
    qkv_wT[idx] = f2bf(qkv_w[c * (3 * CC) + col]);
    return;
  }
  idx -= 27648;
  if (idx < 9216) {                        // proj_wT[col][c]
    int col = idx / CC, c = idx - col * CC;
    proj_wT[idx] = f2bf(proj_w[c * CC + col]);
    return;
  }
  idx -= 9216;
  if (idx < 36864) {                       // fc1_wT[j][c]
    int j = idx / CC, c = idx - j * CC;
    fc1_wT[idx] = f2bf(fc1_w[c * MLPH + j]);
    return;
  }
  idx -= 36864;
  if (idx < 36864) {                       // fc2_wT[c][j]
    int c = idx / MLPH, j = idx - c * MLPH;
    fc2_wT[idx] = f2bf(fc2_w[j * CC + c]);
  }
}

// ---------------- K0b: biasT[head][q][kv] = rpb[ridx(q,kv)*3+head] ----------------
__global__ __launch_bounds__(256) void bias_kernel(const float* __restrict__ rpb,
                                                   float* __restrict__ biasT) {
  int idx = blockIdx.x * 256 + threadIdx.x;
  if (idx >= NHEADS * NN * NN) return;
  int head = idx / (NN * NN);
  int r = idx - head * NN * NN;
  int q = r / NN, kv = r - q * NN;
  int itq = q / 49, rq = q - itq * 49, ihq = rq / 7, iwq = rq - ihq * 7;
  int itk = kv / 49, rk = kv - itk * 49, ihk = rk / 7, iwk = rk - ihk * 7;
  int ridx = (itq - itk + 1) * 169 + (ihq - ihk + 6) * 13 + (iwq - iwk + 6);
  biasT[idx] = rpb[ridx * NHEADS + head];
}

// ---------------- K0c: LN1 + shift-roll + window gather -> xnw[widx][112][96] bf16 ----------------
__global__ __launch_bounds__(256) void ln1_kernel(
    const float* __restrict__ x, const float* __restrict__ g1, const float* __restrict__ b1,
    u16* __restrict__ xnw)
{
  const int tid = threadIdx.x;
  const int row = blockIdx.x * 64 + (tid >> 2);   // 0 .. NWIN*112-1
  const int qd = tid & 3;                          // quarter: 24 channels
  const int widx = row / 112;
  const int n = row - widx * 112;
  u16* dst = xnw + (size_t)row * CC + qd * 24;
  if (n >= NN) {                                   // pad row -> zeros
    uint4 z = {0u, 0u, 0u, 0u};
    *(uint4*)(dst) = z; *(uint4*)(dst + 8) = z; *(uint4*)(dst + 16) = z;
    return;
  }
  int it = n / 49, r = n - it * 49, ih = r / 7, iw = r - ih * 7;
  int ww = widx & 15, hw = (widx >> 4) & 15, tw = widx >> 8;
  int t = tw * 2 + it + 1; if (t >= TT) t -= TT;
  int h = hw * 7 + ih + 3; if (h >= HH) h -= HH;
  int w = ww * 7 + iw + 3; if (w >= WD) w -= WD;
  const float* src = x + ((size_t)(t * HH + h) * WD + w) * CC + qd * 24;
  float v[24];
  #pragma unroll
  for (int i = 0; i < 24; i += 4) {
    float4 f = *(const float4*)(src + i);
    v[i] = f.x; v[i + 1] = f.y; v[i + 2] = f.z; v[i + 3] = f.w;
  }
  float sm = 0.f;
  #pragma unroll
  for (int i = 0; i < 24; ++i) sm += v[i];
  sm += __shfl_xor(sm, 1, 64);
  sm += __shfl_xor(sm, 2, 64);
  float mu = sm * (1.f / CC);
  float sq = 0.f;
  #pragma unroll
  for (int i = 0; i < 24; ++i) { float d = v[i] - mu; sq += d * d; }
  sq += __shfl_xor(sq, 1, 64);
  sq += __shfl_xor(sq, 2, 64);
  float inv = rsqrtf(sq * (1.f / CC) + 1e-5f);
  u16 o[24];
  #pragma unroll
  for (int i = 0; i < 24; ++i) {
    int c = qd * 24 + i;
    o[i] = f2bf((v[i] - mu) * inv * g1[c] + b1[c]);
  }
  *(uint4*)(dst)      = *(const uint4*)(o);
  *(uint4*)(dst + 8)  = *(const uint4*)(o + 8);
  *(uint4*)(dst + 16) = *(const uint4*)(o + 16);
}

// ---------------- K1: per-(window,head) QKV + attention (MFMA) ----------------
__global__ __launch_bounds__(256, 4) void attn_kernel(
    const u16* __restrict__ xnw, const u16* __restrict__ qkv_wT, const float* __restrict__ qkv_b,
    const float* __restrict__ biasT, u16* __restrict__ att)
{
  // union buffer: phases 1-2 -> sQ[112][40] + sK[112][40]; phases 3-4 -> sP[112][136]
  __shared__ __align__(16) u16 sUni[112 * SVP];   // 30464 B
  __shared__ __align__(16) u16 sVt[32 * SVP];     //  8704 B  [d][kv]
  __shared__ int sReg[112];

  u16* sQ = sUni;
  u16* sK = sUni + 112 * SQP;
  u16* sP = sUni;

  const int tid  = threadIdx.x;
  const int bid  = blockIdx.x;
  const int widx = bid / 3;
  const int head = bid - widx * 3;
  const int ww = widx & 15, hw = (widx >> 4) & 15, tw = widx >> 8;
  const bool bnd = (tw == 7) || (hw == 15) || (ww == 15);
  const int wid = tid >> 6;          // wave 0..3
  const int lane = tid & 63;
  const int g  = lane >> 4;          // lane group 0..3
  const int cl = lane & 15;          // col-in-tile

  // ---- phase 0: zero sVt (pad kv cols must be 0) + region ids
  for (int i = tid; i < 32 * SVP / 2; i += 256) ((u32*)sVt)[i] = 0;
  if (tid < 112) {
    int n = tid;
    int reg = 0;
    if (n < NN) {
      int it = n / 49, r = n - it * 49, ih = r / 7, iw = r - ih * 7;
      int ts = tw * 2 + it, hs = hw * 7 + ih, ws2 = ww * 7 + iw;
      int rt = ts < TT - 2 ? 0 : (ts < TT - 1 ? 1 : 2);
      int rh = hs < HH - 7 ? 0 : (hs < HH - 3 ? 1 : 2);
      int rw = ws2 < WD - 7 ? 0 : (ws2 < WD - 3 ? 1 : 2);
      reg = rt * 9 + rh * 3 + rw;
    }
    sReg[n] = reg;
  }
  __syncthreads();

  // ---- phase 1: QKV slice for this head (A-frags straight from global; D -> sQ/sK/sVt)
  {
    const float scale = 0.17677669529663687f;   // 32^-0.5
    #pragma unroll
    for (int mi = 0; mi < 2; ++mi) {
      const int mt = wid + mi * 4;
      if (mt < 7) {
        const u16* arow = xnw + ((size_t)widx * 112 + mt * 16 + cl) * CC + 8 * g;
        bf16x8 a0 = *(const bf16x8*)(arow);
        bf16x8 a1 = *(const bf16x8*)(arow + 32);
        bf16x8 a2 = *(const bf16x8*)(arow + 64);
        #pragma unroll
        for (int nt = 0; nt < 6; ++nt) {
          const int sec = nt >> 1;                      // 0=Q 1=K 2=V
          const int col = sec * 96 + head * 32 + (nt & 1) * 16 + cl;
          const u16* brow = qkv_wT + (size_t)col * CC + 8 * g;
          f32x4 acc = {0.f, 0.f, 0.f, 0.f};
          acc = MFMA16(a0, *(const bf16x8*)(brow), acc);
          acc = MFMA16(a1, *(const bf16x8*)(brow + 32), acc);
          acc = MFMA16(a2, *(const bf16x8*)(brow + 64), acc);
          const float bias = qkv_b[col];
          #pragma unroll
          for (int r = 0; r < 4; ++r) {
            const int row = mt * 16 + 4 * g + r;
            const float v = acc[r] + bias;
            if (sec == 0)      sQ[row * SQP + (nt & 1) * 16 + cl] = f2bf(v * scale);
            else if (sec == 1) sK[row * SQP + (nt & 1) * 16 + cl] = f2bf(v);
            else               sVt[((nt & 1) * 16 + cl) * SVP + row] = f2bf(v);
          }
        }
      }
    }
  }
  __syncthreads();

  // ---- phase 2: QK^T (MFMA, K=32) + bias/mask + in-register softmax
  float sv[2][7][4];
  #pragma unroll
  for (int mi = 0; mi < 2; ++mi) {
    const int mt = wid + mi * 4;
    if (mt >= 7) continue;
    bf16x8 a = *(const bf16x8*)&sQ[(mt * 16 + cl) * SQP + 8 * g];
    #pragma unroll
    for (int nt = 0; nt < 7; ++nt) {
      bf16x8 b = *(const bf16x8*)&sK[(nt * 16 + cl) * SQP + 8 * g];
      f32x4 acc = {0.f, 0.f, 0.f, 0.f};
      acc = MFMA16(a, b, acc);
      #pragma unroll
      for (int r = 0; r < 4; ++r) sv[mi][nt][r] = acc[r];
    }
    const int q0 = mt * 16 + 4 * g;
    #pragma unroll
    for (int nt = 0; nt < 7; ++nt) {
      const int kv = nt * 16 + cl;
      #pragma unroll
      for (int r = 0; r < 4; ++r) {
        const int q = q0 + r;
        float v = sv[mi][nt][r];
        if (kv < NN) {
          if (q < NN) {
            v += biasT[((head * NN + q)) * NN + kv];
            if (bnd && sReg[q] != sReg[kv]) v -= 100.f;
          }
        } else {
          v = -1e30f;
        }
        sv[mi][nt][r] = v;
      }
    }
    #pragma unroll
    for (int r = 0; r < 4; ++r) {
      float mx = sv[mi][0][r];
      #pragma unroll
      for (int nt = 1; nt < 7; ++nt) mx = fmaxf(mx, sv[mi][nt][r]);
      #pragma unroll
      for (int d = 1; d < 16; d <<= 1) mx = fmaxf(mx, __shfl_xor(mx, d, 64));
      float sm = 0.f;
      #pragma unroll
      for (int nt = 0; nt < 7; ++nt) { float p = __expf(sv[mi][nt][r] - mx); sv[mi][nt][r] = p; sm += p; }
      #pragma unroll
      for (int d = 1; d < 16; d <<= 1) sm += __shfl_xor(sm, d, 64);
      const float inv = 1.f / sm;
      #pragma unroll
      for (int nt = 0; nt < 7; ++nt) sv[mi][nt][r] *= inv;
    }
  }
  __syncthreads();   // all Q/K reads complete before P overwrites the union buffer

  // ---- phase 3: write P (bf16) + zero pad cols 112..127
  #pragma unroll
  for (int mi = 0; mi < 2; ++mi) {
    const int mt = wid + mi * 4;
    if (mt >= 7) continue;
    #pragma unroll
    for (int r = 0; r < 4; ++r) {
      const int q = mt * 16 + 4 * g + r;
      u16* prow = &sP[q * SVP];
      #pragma unroll
      for (int nt = 0; nt < 7; ++nt) prow[nt * 16 + cl] = f2bf(sv[mi][nt][r]);
      prow[112 + cl] = 0;
    }
  }
  __syncthreads();

  // ---- phase 4: PV (MFMA, K=128) + store
  for (int t = wid; t < 14; t += 4) {
    const int mt = t >> 1, ntd = t & 1;
    f32x4 acc = {0.f, 0.f, 0.f, 0.f};
    #pragma unroll
    for (int ks = 0; ks < 4; ++ks) {
      bf16x8 a = *(const bf16x8*)&sP[(mt * 16 + cl) * SVP + ks * 32 + 8 * g];
      bf16x8 b = *(const bf16x8*)&sVt[(ntd * 16 + cl) * SVP + ks * 32 + 8 * g];
      acc = MFMA16(a, b, acc);
    }
    #pragma unroll
    for (int r = 0; r < 4; ++r) {
      const int q = mt * 16 + 4 * g + r;
      if (q < NN)
        att[((size_t)widx * NN + q) * CC + head * 32 + ntd * 16 + cl] = f2bf(acc[r]);
    }
  }
}

// ---------------- K2: fused proj + residual + LN2 + FC1 + GELU + FC2 + residual ----------------
// r10 structure (32 tok, 256 thr, 5 phases) with sX1 ALIASED into sH at +8192B:
// LDS 38144 -> 31744 B => 5 blocks/CU. sA occupies sH[0..6656B); sX1 at sH[8192..14592B);
// both dead before P3 overwrites sH (barriers after P1 and P2 order this).
__global__ __launch_bounds__(256, 4) void pm_kernel(
    const u16* __restrict__ att, const u16* __restrict__ proj_wT, const float* __restrict__ proj_b,
    const float* __restrict__ x,
    const float* __restrict__ g2, const float* __restrict__ b2,
    const u16* __restrict__ fc1_wT, const float* __restrict__ fc1_b,
    const u16* __restrict__ fc2_wT, const float* __restrict__ fc2_b,
    float* __restrict__ out)
{
  __shared__ __align__(16) u16 sH [32 * SHP];    // 25088 B (sA and sX1 alias inside)
  __shared__ __align__(16) u16 sXn[32 * SXP];    //  6656 B
  // total 31744 B -> 5 blocks/CU

  u16* sA  = sH;          // [32][SXP] attention-output tile  (bytes 0..6656)
  u16* sX1 = sH + 4096;   // [32][SX1P] x1 bf16 for LN2       (bytes 8192..14592)

  const int tid  = threadIdx.x;
  const int base = blockIdx.x * 32;              // window-token base
  const int wid = tid >> 6, lane = tid & 63, g = lane >> 4, cl = lane & 15;
  const int mt  = wid & 1;          // m-tile (16 tokens)
  const int hnt = wid >> 1;         // nt-range half

  // ---- P-1: natural-row indices + EARLY x-residual prefetch (hides under P0+P1)
  u32 nr[4];
  #pragma unroll
  for (int r = 0; r < 4; ++r) {
    int tok = base + mt * 16 + 4 * g + r;
    int widx = tok / NN, n = tok - widx * NN;
    int ww = widx & 15, hw = (widx >> 4) & 15, tw = widx >> 8;
    int it = n / 49, rr = n - it * 49, ih = rr / 7, iw = rr - ih * 7;
    int t = tw * 2 + it + 1; if (t >= TT) t -= TT;
    int h = hw * 7 + ih + 3; if (h >= HH) h -= HH;
    int w = ww * 7 + iw + 3; if (w >= WD) w -= WD;
    nr[r] = (u32)((t * HH + h) * WD + w);
  }
  float xres[3][4];
  #pragma unroll
  for (int j = 0; j < 3; ++j) {
    const int col = (hnt * 3 + j) * 16 + cl;
    #pragma unroll
    for (int r = 0; r < 4; ++r)
      xres[j][r] = x[(size_t)nr[r] * CC + col];
  }

  // ---- P0: att tile load -> sA
  for (int e = tid; e < 32 * 12; e += 256) {
    int tok = e / 12, kb = e - tok * 12;
    *(uint4*)&sA[tok * SXP + kb * 8] =
        ((const uint4*)att)[(size_t)(base + tok) * 12 + kb];
  }
  __syncthreads();

  // ---- P1: proj GEMM [32x96]@[96x96] + x residual -> x1 regs + sX1 (bf16)
  float x1v[3][4];
  {
    const u16* aRow = &sA[(mt * 16 + cl) * SXP + 8 * g];
    bf16x8 a0 = *(const bf16x8*)(aRow);
    bf16x8 a1 = *(const bf16x8*)(aRow + 32);
    bf16x8 a2 = *(const bf16x8*)(aRow + 64);
    #pragma unroll
    for (int j = 0; j < 3; ++j) {
      const int nt = hnt * 3 + j;
      const u16* bRow = proj_wT + (nt * 16 + cl) * CC + 8 * g;
      f32x4 acc = {0.f, 0.f, 0.f, 0.f};
      acc = MFMA16(a0, *(const bf16x8*)(bRow), acc);
      acc = MFMA16(a1, *(const bf16x8*)(bRow + 32), acc);
      acc = MFMA16(a2, *(const bf16x8*)(bRow + 64), acc);
      const float bc = proj_b[nt * 16 + cl];
      #pragma unroll
      for (int r = 0; r < 4; ++r) {
        const int row = mt * 16 + 4 * g + r;
        const float v = acc[r] + bc + xres[j][r];
        x1v[j][r] = v;
        sX1[row * SX1P + nt * 16 + cl] = f2bf(v);
      }
    }
  }
  __syncthreads();   // sA reads + sX1 writes complete

  // ---- P2: LN2 from sX1 (bf16): token = tid>>3, sub = tid&7 (12 ch); 8-lane shfl reduce
  {
    const int tok = tid >> 3, sub = tid & 7;
    const u16* p = &sX1[tok * SX1P + sub * 12];
    float v[12];
    #pragma unroll
    for (int k = 0; k < 6; ++k) {
      u32 u = *(const u32*)(p + 2 * k);
      v[2 * k] = bflo(u); v[2 * k + 1] = bfhi(u);
    }
    float sm = 0.f;
    #pragma unroll
    for (int i = 0; i < 12; ++i) sm += v[i];
    sm += __shfl_xor(sm, 1, 64);
    sm += __shfl_xor(sm, 2, 64);
    sm += __shfl_xor(sm, 4, 64);
    float mu = sm * (1.f / CC);
    float sq = 0.f;
    #pragma unroll
    for (int i = 0; i < 12; ++i) { float d = v[i] - mu; sq += d * d; }
    sq += __shfl_xor(sq, 1, 64);
    sq += __shfl_xor(sq, 2, 64);
    sq += __shfl_xor(sq, 4, 64);
    float inv = rsqrtf(sq * (1.f / CC) + 1e-5f);
    u16 o[12];
    #pragma unroll
    for (int i = 0; i < 12; ++i) {
      int c = sub * 12 + i;
      o[i] = f2bf((v[i] - mu) * inv * g2[c] + b2[c]);
    }
    u16* dst = &sXn[tok * SXP + sub * 12];
    *(uint2*)(dst)     = *(const uint2*)(o);
    *(uint2*)(dst + 4) = *(const uint2*)(o + 4);
    *(uint2*)(dst + 8) = *(const uint2*)(o + 8);
  }
  __syncthreads();   // sX1 reads complete; sH free for P3

  // ---- P3: FC1 full [32x96]@[96x384] + GELU -> sH (wave does nts [hnt*12, +12))
  {
    const u16* aXn = &sXn[(mt * 16 + cl) * SXP + 8 * g];
    bf16x8 xa0 = *(const bf16x8*)(aXn);
    bf16x8 xa1 = *(const bf16x8*)(aXn + 32);
    bf16x8 xa2 = *(const bf16x8*)(aXn + 64);
    const int nt0 = hnt * 12;
    const u16* bPtr = fc1_wT + ((size_t)(nt0 * 16 + cl)) * CC + 8 * g;
    bf16x8 b0 = *(const bf16x8*)(bPtr);
    bf16x8 b1 = *(const bf16x8*)(bPtr + 32);
    bf16x8 b2 = *(const bf16x8*)(bPtr + 64);
    #pragma unroll
    for (int j = 0; j < 12; ++j) {
      bf16x8 c0 = b0, c1 = b1, c2 = b2;
      if (j < 11) {                       // prefetch next nt
        bPtr += 16 * CC;
        b0 = *(const bf16x8*)(bPtr);
        b1 = *(const bf16x8*)(bPtr + 32);
        b2 = *(const bf16x8*)(bPtr + 64);
      }
      f32x4 acc = {0.f, 0.f, 0.f, 0.f};
      acc = MFMA16(xa0, c0, acc);
      acc = MFMA16(xa1, c1, acc);
      acc = MFMA16(xa2, c2, acc);
      const int nt = nt0 + j;
      const float bj = fc1_b[nt * 16 + cl];
      #pragma unroll
      for (int r = 0; r < 4; ++r) {
        float v = acc[r] + bj;
        // tanh-GELU: v*e/(e+1), e = exp(v*(1.59576912 + 0.07135481*v^2))
        float p2 = v * v;
        float a  = v * fmaf(0.07135481f, p2, 1.59576912f);
        float e  = __expf(a);
        float gl = v * e * __builtin_amdgcn_rcpf(e + 1.f);
        sH[(mt * 16 + 4 * g + r) * SHP + nt * 16 + cl] = f2bf(gl);
      }
    }
  }
  __syncthreads();

  // ---- P4: FC2 [32x384]@[384x96] (two 6-frag k-halves) + epilogue
  {
    f32x4 acc2[3];
    #pragma unroll
    for (int j = 0; j < 3; ++j) { f32x4 z = {0.f, 0.f, 0.f, 0.f}; acc2[j] = z; }
    #pragma unroll
    for (int half = 0; half < 2; ++half) {
      const u16* aBase = &sH[(mt * 16 + cl) * SHP + half * 192 + 8 * g];
      bf16x8 a[6];
      #pragma unroll
      for (int ks = 0; ks < 6; ++ks) a[ks] = *(const bf16x8*)(aBase + 32 * ks);
      #pragma unroll
      for (int j = 0; j < 3; ++j) {
        const int nt = hnt * 3 + j;
        const u16* bBase = fc2_wT + (size_t)(nt * 16 + cl) * MLPH + half * 192 + 8 * g;
        #pragma unroll
        for (int ks = 0; ks < 6; ++ks)
          acc2[j] = MFMA16(a[ks], *(const bf16x8*)(bBase + 32 * ks), acc2[j]);
      }
    }
    #pragma unroll
    for (int j = 0; j < 3; ++j) {
      const int nt = hnt * 3 + j;
      const float bc = fc2_b[nt * 16 + cl];
      #pragma unroll
      for (int r = 0; r < 4; ++r) {
        out[(size_t)nr[r] * CC + nt * 16 + cl] = x1v[j][r] + acc2[j][r] + bc;
      }
    }
  }
}

extern "C" void kernel_launch(void* const* d_in, const int* in_sizes, int n_in,
                              void* d_out, int out_size, void* d_ws, size_t ws_size,
                              hipStream_t stream) {
  const float* x      = (const float*)d_in[0];
  const float* g1     = (const float*)d_in[1];
  const float* b1     = (const float*)d_in[2];
  const float* qkv_w  = (const float*)d_in[3];
  const float* qkv_b  = (const float*)d_in[4];
  const float* rpb    = (const float*)d_in[5];
  const float* proj_w = (const float*)d_in[6];
  const float* proj_b = (const float*)d_in[7];
  const float* g2     = (const float*)d_in[8];
  const float* b2     = (const float*)d_in[9];
  const float* fc1_w  = (const float*)d_in[10];
  const float* fc1_b  = (const float*)d_in[11];
  const float* fc2_w  = (const float*)d_in[12];
  const float* fc2_b  = (const float*)d_in[13];

  char* ws = (char*)d_ws;
  u16*   att    = (u16*)ws;                                   // NTOK*96 bf16 = 38.5 MB
  u16*   xnw    = (u16*)(ws + (size_t)NTOK * CC * 2);         // NWIN*112*96 bf16 = 44 MB
  char*  wtail  = ws + (size_t)NTOK * CC * 2 + (size_t)NWIN * 112 * CC * 2;
  float* biasT  = (float*)wtail;                              // 115248 B
  u16*   qkv_wT = (u16*)(wtail + 115248);                     // 55296 B
  u16*   proj_wT= (u16*)(wtail + 115248 + 55296);             // 18432 B
  u16*   fc1_wT = (u16*)(wtail + 115248 + 55296 + 18432);     // 73728 B
  u16*   fc2_wT = (u16*)(wtail + 115248 + 55296 + 18432 + 73728); // 73728 B

  wprep_kernel<<<(27648 + 9216 + 36864 + 36864 + 255) / 256, 256, 0, stream>>>(
      qkv_w, proj_w, fc1_w, fc2_w, qkv_wT, proj_wT, fc1_wT, fc2_wT);
  bias_kernel<<<(NHEADS * NN * NN + 255) / 256, 256, 0, stream>>>(rpb, biasT);
  ln1_kernel<<<NWIN * 112 / 64, 256, 0, stream>>>(x, g1, b1, xnw);
  attn_kernel<<<NWIN * NHEADS, 256, 0, stream>>>(xnw, qkv_wT, qkv_b, biasT, att);
  pm_kernel<<<NTOK / 32, 256, 0, stream>>>(att, proj_wT, proj_b, x, g2, b2,
                                           fc1_wT, fc1_b, fc2_wT, fc2_b, (float*)d_out);
}

// Round 14
// 352.146 us; speedup vs baseline: 1.0199x; 1.0087x over previous
//
#include <hip/hip_runtime.h>
#include <math.h>

#define TT 16
#define HH 112
#define WD 112
#define CC 96
#define NHEADS 3
#define HD 32
#define NN 98          // window tokens 2*7*7
#define NWIN 2048      // 8*16*16
#define NTOK 200704    // T*H*W == NWIN*NN
#define MLPH 384
#define SXP 104        // row stride (bf16) LDS tiles (208B rows, 16B aligned)
#define SQP 40         // row stride (bf16) per-head sQ/sK
#define SVP 136        // row stride (bf16) sVt/sP
#define SHP 392        // row stride (bf16) sH full (384 cols + 8 pad)
#define SX1P 100       // row stride (bf16) sX1

typedef unsigned int  u32;
typedef unsigned short u16;
typedef float f32x4 __attribute__((ext_vector_type(4)));
typedef short bf16x8 __attribute__((ext_vector_type(8)));

__device__ inline u16 f2bf(float f) {
  u32 u = __float_as_uint(f);
  u += 0x7fffu + ((u >> 16) & 1u);
  return (u16)(u >> 16);
}
__device__ inline float bflo(u32 u) { return __uint_as_float(u << 16); }
__device__ inline float bfhi(u32 u) { return __uint_as_float(u & 0xffff0000u); }

#define MFMA16(a, b, c) __builtin_amdgcn_mfma_f32_16x16x32_bf16((a), (b), (c), 0, 0, 0)

// ---------------- K0a: transpose all weights to bf16 col-major ----------------
__global__ __launch_bounds__(256) void wprep_kernel(
    const float* __restrict__ qkv_w, const float* __restrict__ proj_w,
    const float* __restrict__ fc1_w, const float* __restrict__ fc2_w,
    u16* __restrict__ qkv_wT, u16* __restrict__ proj_wT,
    u16* __restrict__ fc1_wT, u16* __restrict__ fc2_wT) {
  int idx = blockIdx.x * 256 + threadIdx.x;
  if (idx < 27648) {                       // qkv_wT[col][c]
    int col = idx / CC, c = idx - col * CC;
    qkv_wT[idx] = f2bf(qkv_w[c * (3 * CC) + col]);
    return;
  }
  idx -= 27648;
  if (idx < 9216) {                        // proj_wT[col][c]
    int col = idx / CC, c = idx - col * CC;
    proj_wT[idx] = f2bf(proj_w[c * CC + col]);
    return;
  }
  idx -= 9216;
  if (idx < 36864) {                       // fc1_wT[j][c]
    int j = idx / CC, c = idx - j * CC;
    fc1_wT[idx] = f2bf(fc1_w[c * MLPH + j]);
    return;
  }
  idx -= 36864;
  if (idx < 36864) {                       // fc2_wT[c][j]
    int c = idx / MLPH, j = idx - c * MLPH;
    fc2_wT[idx] = f2bf(fc2_w[j * CC + c]);
  }
}

// ---------------- K0b: biasT[head][q][kv] = rpb[ridx(q,kv)*3+head] ----------------
__global__ __launch_bounds__(256) void bias_kernel(const float* __restrict__ rpb,
                                                   float* __restrict__ biasT) {
  int idx = blockIdx.x * 256 + threadIdx.x;
  if (idx >= NHEADS * NN * NN) return;
  int head = idx / (NN * NN);
  int r = idx - head * NN * NN;
  int q = r / NN, kv = r - q * NN;
  int itq = q / 49, rq = q - itq * 49, ihq = rq / 7, iwq = rq - ihq * 7;
  int itk = kv / 49, rk = kv - itk * 49, ihk = rk / 7, iwk = rk - ihk * 7;
  int ridx = (itq - itk + 1) * 169 + (ihq - ihk + 6) * 13 + (iwq - iwk + 6);
  biasT[idx] = rpb[ridx * NHEADS + head];
}

// ---------------- K0c: LN1 + shift-roll + window gather -> xnw[widx][112][96] bf16 ----------------
__global__ __launch_bounds__(256) void ln1_kernel(
    const float* __restrict__ x, const float* __restrict__ g1, const float* __restrict__ b1,
    u16* __restrict__ xnw)
{
  const int tid = threadIdx.x;
  const int row = blockIdx.x * 64 + (tid >> 2);   // 0 .. NWIN*112-1
  const int qd = tid & 3;                          // quarter: 24 channels
  const int widx = row / 112;
  const int n = row - widx * 112;
  u16* dst = xnw + (size_t)row * CC + qd * 24;
  if (n >= NN) {                                   // pad row -> zeros
    uint4 z = {0u, 0u, 0u, 0u};
    *(uint4*)(dst) = z; *(uint4*)(dst + 8) = z; *(uint4*)(dst + 16) = z;
    return;
  }
  int it = n / 49, r = n - it * 49, ih = r / 7, iw = r - ih * 7;
  int ww = widx & 15, hw = (widx >> 4) & 15, tw = widx >> 8;
  int t = tw * 2 + it + 1; if (t >= TT) t -= TT;
  int h = hw * 7 + ih + 3; if (h >= HH) h -= HH;
  int w = ww * 7 + iw + 3; if (w >= WD) w -= WD;
  const float* src = x + ((size_t)(t * HH + h) * WD + w) * CC + qd * 24;
  float v[24];
  #pragma unroll
  for (int i = 0; i < 24; i += 4) {
    float4 f = *(const float4*)(src + i);
    v[i] = f.x; v[i + 1] = f.y; v[i + 2] = f.z; v[i + 3] = f.w;
  }
  float sm = 0.f;
  #pragma unroll
  for (int i = 0; i < 24; ++i) sm += v[i];
  sm += __shfl_xor(sm, 1, 64);
  sm += __shfl_xor(sm, 2, 64);
  float mu = sm * (1.f / CC);
  float sq = 0.f;
  #pragma unroll
  for (int i = 0; i < 24; ++i) { float d = v[i] - mu; sq += d * d; }
  sq += __shfl_xor(sq, 1, 64);
  sq += __shfl_xor(sq, 2, 64);
  float inv = rsqrtf(sq * (1.f / CC) + 1e-5f);
  u16 o[24];
  #pragma unroll
  for (int i = 0; i < 24; ++i) {
    int c = qd * 24 + i;
    o[i] = f2bf((v[i] - mu) * inv * g1[c] + b1[c]);
  }
  *(uint4*)(dst)      = *(const uint4*)(o);
  *(uint4*)(dst + 8)  = *(const uint4*)(o + 8);
  *(uint4*)(dst + 16) = *(const uint4*)(o + 16);
}

// ---------------- K1: per-(window,head) QKV + attention (MFMA) ----------------
__global__ __launch_bounds__(256, 4) void attn_kernel(
    const u16* __restrict__ xnw, const u16* __restrict__ qkv_wT, const float* __restrict__ qkv_b,
    const float* __restrict__ biasT, u16* __restrict__ att)
{
  // union buffer: phases 1-2 -> sQ[112][40] + sK[112][40]; phases 3-4 -> sP[112][136]
  __shared__ __align__(16) u16 sUni[112 * SVP];   // 30464 B
  __shared__ __align__(16) u16 sVt[32 * SVP];     //  8704 B  [d][kv]
  __shared__ int sReg[112];

  u16* sQ = sUni;
  u16* sK = sUni + 112 * SQP;
  u16* sP = sUni;

  const int tid  = threadIdx.x;
  const int bid  = blockIdx.x;
  const int widx = bid / 3;
  const int head = bid - widx * 3;
  const int ww = widx & 15, hw = (widx >> 4) & 15, tw = widx >> 8;
  const bool bnd = (tw == 7) || (hw == 15) || (ww == 15);
  const int wid = tid >> 6;          // wave 0..3
  const int lane = tid & 63;
  const int g  = lane >> 4;          // lane group 0..3
  const int cl = lane & 15;          // col-in-tile

  // ---- phase 0: zero sVt (pad kv cols must be 0) + region ids
  for (int i = tid; i < 32 * SVP / 2; i += 256) ((u32*)sVt)[i] = 0;
  if (tid < 112) {
    int n = tid;
    int reg = 0;
    if (n < NN) {
      int it = n / 49, r = n - it * 49, ih = r / 7, iw = r - ih * 7;
      int ts = tw * 2 + it, hs = hw * 7 + ih, ws2 = ww * 7 + iw;
      int rt = ts < TT - 2 ? 0 : (ts < TT - 1 ? 1 : 2);
      int rh = hs < HH - 7 ? 0 : (hs < HH - 3 ? 1 : 2);
      int rw = ws2 < WD - 7 ? 0 : (ws2 < WD - 3 ? 1 : 2);
      reg = rt * 9 + rh * 3 + rw;
    }
    sReg[n] = reg;
  }
  __syncthreads();

  // ---- phase 1: QKV slice for this head (A-frags straight from global; D -> sQ/sK/sVt)
  {
    const float scale = 0.17677669529663687f;   // 32^-0.5
    #pragma unroll
    for (int mi = 0; mi < 2; ++mi) {
      const int mt = wid + mi * 4;
      if (mt < 7) {
        const u16* arow = xnw + ((size_t)widx * 112 + mt * 16 + cl) * CC + 8 * g;
        bf16x8 a0 = *(const bf16x8*)(arow);
        bf16x8 a1 = *(const bf16x8*)(arow + 32);
        bf16x8 a2 = *(const bf16x8*)(arow + 64);
        #pragma unroll
        for (int nt = 0; nt < 6; ++nt) {
          const int sec = nt >> 1;                      // 0=Q 1=K 2=V
          const int col = sec * 96 + head * 32 + (nt & 1) * 16 + cl;
          const u16* brow = qkv_wT + (size_t)col * CC + 8 * g;
          f32x4 acc = {0.f, 0.f, 0.f, 0.f};
          acc = MFMA16(a0, *(const bf16x8*)(brow), acc);
          acc = MFMA16(a1, *(const bf16x8*)(brow + 32), acc);
          acc = MFMA16(a2, *(const bf16x8*)(brow + 64), acc);
          const float bias = qkv_b[col];
          #pragma unroll
          for (int r = 0; r < 4; ++r) {
            const int row = mt * 16 + 4 * g + r;
            const float v = acc[r] + bias;
            if (sec == 0)      sQ[row * SQP + (nt & 1) * 16 + cl] = f2bf(v * scale);
            else if (sec == 1) sK[row * SQP + (nt & 1) * 16 + cl] = f2bf(v);
            else               sVt[((nt & 1) * 16 + cl) * SVP + row] = f2bf(v);
          }
        }
      }
    }
  }
  __syncthreads();

  // ---- phase 2: QK^T (MFMA, K=32) + bias/mask + in-register softmax
  float sv[2][7][4];
  #pragma unroll
  for (int mi = 0; mi < 2; ++mi) {
    const int mt = wid + mi * 4;
    if (mt >= 7) continue;
    bf16x8 a = *(const bf16x8*)&sQ[(mt * 16 + cl) * SQP + 8 * g];
    #pragma unroll
    for (int nt = 0; nt < 7; ++nt) {
      bf16x8 b = *(const bf16x8*)&sK[(nt * 16 + cl) * SQP + 8 * g];
      f32x4 acc = {0.f, 0.f, 0.f, 0.f};
      acc = MFMA16(a, b, acc);
      #pragma unroll
      for (int r = 0; r < 4; ++r) sv[mi][nt][r] = acc[r];
    }
    const int q0 = mt * 16 + 4 * g;
    #pragma unroll
    for (int nt = 0; nt < 7; ++nt) {
      const int kv = nt * 16 + cl;
      #pragma unroll
      for (int r = 0; r < 4; ++r) {
        const int q = q0 + r;
        float v = sv[mi][nt][r];
        if (kv < NN) {
          if (q < NN) {
            v += biasT[((head * NN + q)) * NN + kv];
            if (bnd && sReg[q] != sReg[kv]) v -= 100.f;
          }
        } else {
          v = -1e30f;
        }
        sv[mi][nt][r] = v;
      }
    }
    #pragma unroll
    for (int r = 0; r < 4; ++r) {
      float mx = sv[mi][0][r];
      #pragma unroll
      for (int nt = 1; nt < 7; ++nt) mx = fmaxf(mx, sv[mi][nt][r]);
      #pragma unroll
      for (int d = 1; d < 16; d <<= 1) mx = fmaxf(mx, __shfl_xor(mx, d, 64));
      float sm = 0.f;
      #pragma unroll
      for (int nt = 0; nt < 7; ++nt) { float p = __expf(sv[mi][nt][r] - mx); sv[mi][nt][r] = p; sm += p; }
      #pragma unroll
      for (int d = 1; d < 16; d <<= 1) sm += __shfl_xor(sm, d, 64);
      const float inv = 1.f / sm;
      #pragma unroll
      for (int nt = 0; nt < 7; ++nt) sv[mi][nt][r] *= inv;
    }
  }
  __syncthreads();   // all Q/K reads complete before P overwrites the union buffer

  // ---- phase 3: write P (bf16) + zero pad cols 112..127
  #pragma unroll
  for (int mi = 0; mi < 2; ++mi) {
    const int mt = wid + mi * 4;
    if (mt >= 7) continue;
    #pragma unroll
    for (int r = 0; r < 4; ++r) {
      const int q = mt * 16 + 4 * g + r;
      u16* prow = &sP[q * SVP];
      #pragma unroll
      for (int nt = 0; nt < 7; ++nt) prow[nt * 16 + cl] = f2bf(sv[mi][nt][r]);
      prow[112 + cl] = 0;
    }
  }
  __syncthreads();

  // ---- phase 4: PV (MFMA, K=128) + store
  for (int t = wid; t < 14; t += 4) {
    const int mt = t >> 1, ntd = t & 1;
    f32x4 acc = {0.f, 0.f, 0.f, 0.f};
    #pragma unroll
    for (int ks = 0; ks < 4; ++ks) {
      bf16x8 a = *(const bf16x8*)&sP[(mt * 16 + cl) * SVP + ks * 32 + 8 * g];
      bf16x8 b = *(const bf16x8*)&sVt[(ntd * 16 + cl) * SVP + ks * 32 + 8 * g];
      acc = MFMA16(a, b, acc);
    }
    #pragma unroll
    for (int r = 0; r < 4; ++r) {
      const int q = mt * 16 + 4 * g + r;
      if (q < NN)
        att[((size_t)widx * NN + q) * CC + head * 32 + ntd * 16 + cl] = f2bf(acc[r]);
    }
  }
}

// ---------------- K2: fused proj + residual + LN2 + FC1 + GELU + FC2 + residual ----------------
// r13 structure + DEEP LOAD BANKS: proj-B prefetched at top; FC1 ping-pong 3-nt banks
// (bankA issued before the P2->P3 barrier); FC2 next-nt prefetch with pre-barrier first burst.
__global__ __launch_bounds__(256, 4) void pm_kernel(
    const u16* __restrict__ att, const u16* __restrict__ proj_wT, const float* __restrict__ proj_b,
    const float* __restrict__ x,
    const float* __restrict__ g2, const float* __restrict__ b2,
    const u16* __restrict__ fc1_wT, const float* __restrict__ fc1_b,
    const u16* __restrict__ fc2_wT, const float* __restrict__ fc2_b,
    float* __restrict__ out)
{
  __shared__ __align__(16) u16 sH [32 * SHP];    // 25088 B (sA and sX1 alias inside)
  __shared__ __align__(16) u16 sXn[32 * SXP];    //  6656 B
  // total 31744 B -> 5 blocks/CU

  u16* sA  = sH;          // [32][SXP] attention-output tile  (bytes 0..6656)
  u16* sX1 = sH + 4096;   // [32][SX1P] x1 bf16 for LN2       (bytes 8192..14592)

  const int tid  = threadIdx.x;
  const int base = blockIdx.x * 32;              // window-token base
  const int wid = tid >> 6, lane = tid & 63, g = lane >> 4, cl = lane & 15;
  const int mt  = wid & 1;          // m-tile (16 tokens)
  const int hnt = wid >> 1;         // nt-range half

  // ---- P-1: natural-row indices + EARLY x-residual + proj-B prefetch
  u32 nr[4];
  #pragma unroll
  for (int r = 0; r < 4; ++r) {
    int tok = base + mt * 16 + 4 * g + r;
    int widx = tok / NN, n = tok - widx * NN;
    int ww = widx & 15, hw = (widx >> 4) & 15, tw = widx >> 8;
    int it = n / 49, rr = n - it * 49, ih = rr / 7, iw = rr - ih * 7;
    int t = tw * 2 + it + 1; if (t >= TT) t -= TT;
    int h = hw * 7 + ih + 3; if (h >= HH) h -= HH;
    int w = ww * 7 + iw + 3; if (w >= WD) w -= WD;
    nr[r] = (u32)((t * HH + h) * WD + w);
  }
  float xres[3][4];
  #pragma unroll
  for (int j = 0; j < 3; ++j) {
    const int col = (hnt * 3 + j) * 16 + cl;
    #pragma unroll
    for (int r = 0; r < 4; ++r)
      xres[j][r] = x[(size_t)nr[r] * CC + col];
  }
  bf16x8 wp[9];   // proj B-frags for this wave's 3 nt, consumed in P1
  {
    const u16* bp = proj_wT + ((size_t)((hnt * 3) * 16 + cl)) * CC + 8 * g;
    #pragma unroll
    for (int j = 0; j < 3; ++j) {
      wp[3 * j + 0] = *(const bf16x8*)(bp);
      wp[3 * j + 1] = *(const bf16x8*)(bp + 32);
      wp[3 * j + 2] = *(const bf16x8*)(bp + 64);
      bp += 16 * CC;
    }
  }

  // ---- P0: att tile load -> sA
  for (int e = tid; e < 32 * 12; e += 256) {
    int tok = e / 12, kb = e - tok * 12;
    *(uint4*)&sA[tok * SXP + kb * 8] =
        ((const uint4*)att)[(size_t)(base + tok) * 12 + kb];
  }
  __syncthreads();

  // ---- P1: proj GEMM [32x96]@[96x96] + x residual -> x1 regs + sX1 (bf16)
  float x1v[3][4];
  {
    const u16* aRow = &sA[(mt * 16 + cl) * SXP + 8 * g];
    bf16x8 a0 = *(const bf16x8*)(aRow);
    bf16x8 a1 = *(const bf16x8*)(aRow + 32);
    bf16x8 a2 = *(const bf16x8*)(aRow + 64);
    #pragma unroll
    for (int j = 0; j < 3; ++j) {
      const int nt = hnt * 3 + j;
      f32x4 acc = {0.f, 0.f, 0.f, 0.f};
      acc = MFMA16(a0, wp[3 * j + 0], acc);
      acc = MFMA16(a1, wp[3 * j + 1], acc);
      acc = MFMA16(a2, wp[3 * j + 2], acc);
      const float bc = proj_b[nt * 16 + cl];
      #pragma unroll
      for (int r = 0; r < 4; ++r) {
        const int row = mt * 16 + 4 * g + r;
        const float v = acc[r] + bc + xres[j][r];
        x1v[j][r] = v;
        sX1[row * SX1P + nt * 16 + cl] = f2bf(v);
      }
    }
  }
  __syncthreads();   // sA reads + sX1 writes complete

  // ---- P2: LN2 from sX1 (bf16): token = tid>>3, sub = tid&7 (12 ch); 8-lane shfl reduce
  {
    const int tok = tid >> 3, sub = tid & 7;
    const u16* p = &sX1[tok * SX1P + sub * 12];
    float v[12];
    #pragma unroll
    for (int k = 0; k < 6; ++k) {
      u32 u = *(const u32*)(p + 2 * k);
      v[2 * k] = bflo(u); v[2 * k + 1] = bfhi(u);
    }
    float sm = 0.f;
    #pragma unroll
    for (int i = 0; i < 12; ++i) sm += v[i];
    sm += __shfl_xor(sm, 1, 64);
    sm += __shfl_xor(sm, 2, 64);
    sm += __shfl_xor(sm, 4, 64);
    float mu = sm * (1.f / CC);
    float sq = 0.f;
    #pragma unroll
    for (int i = 0; i < 12; ++i) { float d = v[i] - mu; sq += d * d; }
    sq += __shfl_xor(sq, 1, 64);
    sq += __shfl_xor(sq, 2, 64);
    sq += __shfl_xor(sq, 4, 64);
    float inv = rsqrtf(sq * (1.f / CC) + 1e-5f);
    u16 o[12];
    #pragma unroll
    for (int i = 0; i < 12; ++i) {
      int c = sub * 12 + i;
      o[i] = f2bf((v[i] - mu) * inv * g2[c] + b2[c]);
    }
    u16* dst = &sXn[tok * SXP + sub * 12];
    *(uint2*)(dst)     = *(const uint2*)(o);
    *(uint2*)(dst + 4) = *(const uint2*)(o + 4);
    *(uint2*)(dst + 8) = *(const uint2*)(o + 8);
  }

  // FC1 bank A (nt0..nt0+2) issued BEFORE the barrier -> latency fully hidden
  const int nt0 = hnt * 12;
  bf16x8 wA[9], wB[9];
  {
    const u16* bp = fc1_wT + ((size_t)(nt0 * 16 + cl)) * CC + 8 * g;
    #pragma unroll
    for (int k = 0; k < 3; ++k) {
      wA[3 * k + 0] = *(const bf16x8*)(bp);
      wA[3 * k + 1] = *(const bf16x8*)(bp + 32);
      wA[3 * k + 2] = *(const bf16x8*)(bp + 64);
      bp += 16 * CC;
    }
  }
  __syncthreads();   // sX1 reads complete; sH free for P3

  // ---- P3: FC1 [32x96]@[96x384] + GELU -> sH (ping-pong 3-nt banks)
  {
    const u16* aXn = &sXn[(mt * 16 + cl) * SXP + 8 * g];
    bf16x8 xa0 = *(const bf16x8*)(aXn);
    bf16x8 xa1 = *(const bf16x8*)(aXn + 32);
    bf16x8 xa2 = *(const bf16x8*)(aXn + 64);

#define FC1_LOAD(bank, cb) { \
    const u16* bp_ = fc1_wT + ((size_t)(((cb) * 16 + cl))) * CC + 8 * g; \
    _Pragma("unroll") \
    for (int k_ = 0; k_ < 3; ++k_) { \
      bank[3 * k_ + 0] = *(const bf16x8*)(bp_); \
      bank[3 * k_ + 1] = *(const bf16x8*)(bp_ + 32); \
      bank[3 * k_ + 2] = *(const bf16x8*)(bp_ + 64); \
      bp_ += 16 * CC; } }

#define FC1_COMP(bank, cb) { \
    _Pragma("unroll") \
    for (int k_ = 0; k_ < 3; ++k_) { \
      f32x4 acc = {0.f, 0.f, 0.f, 0.f}; \
      acc = MFMA16(xa0, bank[3 * k_ + 0], acc); \
      acc = MFMA16(xa1, bank[3 * k_ + 1], acc); \
      acc = MFMA16(xa2, bank[3 * k_ + 2], acc); \
      const int nt_ = (cb) + k_; \
      const float bj_ = fc1_b[nt_ * 16 + cl]; \
      _Pragma("unroll") \
      for (int r_ = 0; r_ < 4; ++r_) { \
        float v_ = acc[r_] + bj_; \
        float p2_ = v_ * v_; \
        float a_  = v_ * fmaf(0.07135481f, p2_, 1.59576912f); \
        float e_  = __expf(a_); \
        float gl_ = v_ * e_ * __builtin_amdgcn_rcpf(e_ + 1.f); \
        sH[(mt * 16 + 4 * g + r_) * SHP + nt_ * 16 + cl] = f2bf(gl_); } } }

    FC1_LOAD(wB, nt0 + 3);
    FC1_COMP(wA, nt0);
    FC1_LOAD(wA, nt0 + 6);
    FC1_COMP(wB, nt0 + 3);
    FC1_LOAD(wB, nt0 + 9);
    FC1_COMP(wA, nt0 + 6);
    FC1_COMP(wB, nt0 + 9);
#undef FC1_LOAD
#undef FC1_COMP
  }

  // FC2 first burst (half 0, first nt) issued BEFORE the barrier
  bf16x8 w2[6];
  {
    const u16* bb = fc2_wT + (size_t)((hnt * 3) * 16 + cl) * MLPH + 8 * g;
    #pragma unroll
    for (int ks = 0; ks < 6; ++ks) w2[ks] = *(const bf16x8*)(bb + 32 * ks);
  }
  __syncthreads();

  // ---- P4: FC2 [32x384]@[384x96] (two k-halves, next-nt B prefetch) + epilogue
  {
    f32x4 acc2[3];
    #pragma unroll
    for (int j = 0; j < 3; ++j) { f32x4 z = {0.f, 0.f, 0.f, 0.f}; acc2[j] = z; }
    #pragma unroll
    for (int half = 0; half < 2; ++half) {
      const u16* aBase = &sH[(mt * 16 + cl) * SHP + half * 192 + 8 * g];
      bf16x8 a[6];
      #pragma unroll
      for (int ks = 0; ks < 6; ++ks) a[ks] = *(const bf16x8*)(aBase + 32 * ks);
      #pragma unroll
      for (int j = 0; j < 3; ++j) {
        bf16x8 c[6];
        #pragma unroll
        for (int ks = 0; ks < 6; ++ks) c[ks] = w2[ks];
        // prefetch next (nt, half) pair's B-frags
        if (!(half == 1 && j == 2)) {
          const int nj = (j == 2) ? 0 : j + 1;
          const int nh = (j == 2) ? 1 : half;
          const u16* bb = fc2_wT + (size_t)((hnt * 3 + nj) * 16 + cl) * MLPH + nh * 192 + 8 * g;
          #pragma unroll
          for (int ks = 0; ks < 6; ++ks) w2[ks] = *(const bf16x8*)(bb + 32 * ks);
        }
        #pragma unroll
        for (int ks = 0; ks < 6; ++ks)
          acc2[j] = MFMA16(a[ks], c[ks], acc2[j]);
      }
    }
    #pragma unroll
    for (int j = 0; j < 3; ++j) {
      const int nt = hnt * 3 + j;
      const float bc = fc2_b[nt * 16 + cl];
      #pragma unroll
      for (int r = 0; r < 4; ++r) {
        out[(size_t)nr[r] * CC + nt * 16 + cl] = x1v[j][r] + acc2[j][r] + bc;
      }
    }
  }
}

extern "C" void kernel_launch(void* const* d_in, const int* in_sizes, int n_in,
                              void* d_out, int out_size, void* d_ws, size_t ws_size,
                              hipStream_t stream) {
  const float* x      = (const float*)d_in[0];
  const float* g1     = (const float*)d_in[1];
  const float* b1     = (const float*)d_in[2];
  const float* qkv_w  = (const float*)d_in[3];
  const float* qkv_b  = (const float*)d_in[4];
  const float* rpb    = (const float*)d_in[5];
  const float* proj_w = (const float*)d_in[6];
  const float* proj_b = (const float*)d_in[7];
  const float* g2     = (const float*)d_in[8];
  const float* b2     = (const float*)d_in[9];
  const float* fc1_w  = (const float*)d_in[10];
  const float* fc1_b  = (const float*)d_in[11];
  const float* fc2_w  = (const float*)d_in[12];
  const float* fc2_b  = (const float*)d_in[13];

  char* ws = (char*)d_ws;
  u16*   att    = (u16*)ws;                                   // NTOK*96 bf16 = 38.5 MB
  u16*   xnw    = (u16*)(ws + (size_t)NTOK * CC * 2);         // NWIN*112*96 bf16 = 44 MB
  char*  wtail  = ws + (size_t)NTOK * CC * 2 + (size_t)NWIN * 112 * CC * 2;
  float* biasT  = (float*)wtail;                              // 115248 B
  u16*   qkv_wT = (u16*)(wtail + 115248);                     // 55296 B
  u16*   proj_wT= (u16*)(wtail + 115248 + 55296);             // 18432 B
  u16*   fc1_wT = (u16*)(wtail + 115248 + 55296 + 18432);     // 73728 B
  u16*   fc2_wT = (u16*)(wtail + 115248 + 55296 + 18432 + 73728); // 73728 B

  wprep_kernel<<<(27648 + 9216 + 36864 + 36864 + 255) / 256, 256, 0, stream>>>(
      qkv_w, proj_w, fc1_w, fc2_w, qkv_wT, proj_wT, fc1_wT, fc2_wT);
  bias_kernel<<<(NHEADS * NN * NN + 255) / 256, 256, 0, stream>>>(rpb, biasT);
  ln1_kernel<<<NWIN * 112 / 64, 256, 0, stream>>>(x, g1, b1, xnw);
  attn_kernel<<<NWIN * NHEADS, 256, 0, stream>>>(xnw, qkv_wT, qkv_b, biasT, att);
  pm_kernel<<<NTOK / 32, 256, 0, stream>>>(att, proj_wT, proj_b, x, g2, b2,
                                           fc1_wT, fc1_b, fc2_wT, fc2_b, (float*)d_out);
}

// Round 15
// 278.036 us; speedup vs baseline: 1.2917x; 1.2665x over previous
//
#include <hip/hip_runtime.h>
#include <math.h>

#define TT 16
#define HH 112
#define WD 112
#define CC 96
#define NHEADS 3
#define HD 32
#define NN 98          // window tokens 2*7*7
#define NWIN 2048      // 8*16*16
#define NTOK 200704    // T*H*W == NWIN*NN
#define MLPH 384
#define SXP 104        // row stride (bf16) LDS tiles (208B rows, 16B aligned)
#define SQP 40         // row stride (bf16) per-head sQ/sK
#define SVP 136        // row stride (bf16) sVt/sP
#define SHP 392        // row stride (bf16) sH full (384 cols + 8 pad)
#define SX1P 100       // row stride (bf16) sX1

typedef unsigned int  u32;
typedef unsigned short u16;
typedef float f32x4 __attribute__((ext_vector_type(4)));
typedef short bf16x8 __attribute__((ext_vector_type(8)));

__device__ inline u16 f2bf(float f) {
  u32 u = __float_as_uint(f);
  u += 0x7fffu + ((u >> 16) & 1u);
  return (u16)(u >> 16);
}
__device__ inline float bflo(u32 u) { return __uint_as_float(u << 16); }
__device__ inline float bfhi(u32 u) { return __uint_as_float(u & 0xffff0000u); }

#define MFMA16(a, b, c) __builtin_amdgcn_mfma_f32_16x16x32_bf16((a), (b), (c), 0, 0, 0)

// ---------------- K0a: transpose all weights to bf16 col-major ----------------
__global__ __launch_bounds__(256) void wprep_kernel(
    const float* __restrict__ qkv_w, const float* __restrict__ proj_w,
    const float* __restrict__ fc1_w, const float* __restrict__ fc2_w,
    u16* __restrict__ qkv_wT, u16* __restrict__ proj_wT,
    u16* __restrict__ fc1_wT, u16* __restrict__ fc2_wT) {
  int idx = blockIdx.x * 256 + threadIdx.x;
  if (idx < 27648) {                       // qkv_wT[col][c]
    int col = idx / CC, c = idx - col * CC;
    qkv_wT[idx] = f2bf(qkv_w[c * (3 * CC) + col]);
    return;
  }
  idx -= 27648;
  if (idx < 9216) {                        // proj_wT[col][c]
    int col = idx / CC, c = idx - col * CC;
    proj_wT[idx] = f2bf(proj_w[c * CC + col]);
    return;
  }
  idx -= 9216;
  if (idx < 36864) {                       // fc1_wT[j][c]
    int j = idx / CC, c = idx - j * CC;
    fc1_wT[idx] = f2bf(fc1_w[c * MLPH + j]);
    return;
  }
  idx -= 36864;
  if (idx < 36864) {                       // fc2_wT[c][j]
    int c = idx / MLPH, j = idx - c * MLPH;
    fc2_wT[idx] = f2bf(fc2_w[j * CC + c]);
  }
}

// ---------------- K0b: biasT[head][q][kv] = rpb[ridx(q,kv)*3+head] ----------------
__global__ __launch_bounds__(256) void bias_kernel(const float* __restrict__ rpb,
                                                   float* __restrict__ biasT) {
  int idx = blockIdx.x * 256 + threadIdx.x;
  if (idx >= NHEADS * NN * NN) return;
  int head = idx / (NN * NN);
  int r = idx - head * NN * NN;
  int q = r / NN, kv = r - q * NN;
  int itq = q / 49, rq = q - itq * 49, ihq = rq / 7, iwq = rq - ihq * 7;
  int itk = kv / 49, rk = kv - itk * 49, ihk = rk / 7, iwk = rk - ihk * 7;
  int ridx = (itq - itk + 1) * 169 + (ihq - ihk + 6) * 13 + (iwq - iwk + 6);
  biasT[idx] = rpb[ridx * NHEADS + head];
}

// ---------------- K0c: LN1 + shift-roll + window gather -> xnw[widx][112][96] bf16 ----------------
__global__ __launch_bounds__(256) void ln1_kernel(
    const float* __restrict__ x, const float* __restrict__ g1, const float* __restrict__ b1,
    u16* __restrict__ xnw)
{
  const int tid = threadIdx.x;
  const int row = blockIdx.x * 64 + (tid >> 2);   // 0 .. NWIN*112-1
  const int qd = tid & 3;                          // quarter: 24 channels
  const int widx = row / 112;
  const int n = row - widx * 112;
  u16* dst = xnw + (size_t)row * CC + qd * 24;
  if (n >= NN) {                                   // pad row -> zeros
    uint4 z = {0u, 0u, 0u, 0u};
    *(uint4*)(dst) = z; *(uint4*)(dst + 8) = z; *(uint4*)(dst + 16) = z;
    return;
  }
  int it = n / 49, r = n - it * 49, ih = r / 7, iw = r - ih * 7;
  int ww = widx & 15, hw = (widx >> 4) & 15, tw = widx >> 8;
  int t = tw * 2 + it + 1; if (t >= TT) t -= TT;
  int h = hw * 7 + ih + 3; if (h >= HH) h -= HH;
  int w = ww * 7 + iw + 3; if (w >= WD) w -= WD;
  const float* src = x + ((size_t)(t * HH + h) * WD + w) * CC + qd * 24;
  float v[24];
  #pragma unroll
  for (int i = 0; i < 24; i += 4) {
    float4 f = *(const float4*)(src + i);
    v[i] = f.x; v[i + 1] = f.y; v[i + 2] = f.z; v[i + 3] = f.w;
  }
  float sm = 0.f;
  #pragma unroll
  for (int i = 0; i < 24; ++i) sm += v[i];
  sm += __shfl_xor(sm, 1, 64);
  sm += __shfl_xor(sm, 2, 64);
  float mu = sm * (1.f / CC);
  float sq = 0.f;
  #pragma unroll
  for (int i = 0; i < 24; ++i) { float d = v[i] - mu; sq += d * d; }
  sq += __shfl_xor(sq, 1, 64);
  sq += __shfl_xor(sq, 2, 64);
  float inv = rsqrtf(sq * (1.f / CC) + 1e-5f);
  u16 o[24];
  #pragma unroll
  for (int i = 0; i < 24; ++i) {
    int c = qd * 24 + i;
    o[i] = f2bf((v[i] - mu) * inv * g1[c] + b1[c]);
  }
  *(uint4*)(dst)      = *(const uint4*)(o);
  *(uint4*)(dst + 8)  = *(const uint4*)(o + 8);
  *(uint4*)(dst + 16) = *(const uint4*)(o + 16);
}

// ---------------- K1: per-(window,head) QKV + attention (MFMA) ----------------
__global__ __launch_bounds__(256, 4) void attn_kernel(
    const u16* __restrict__ xnw, const u16* __restrict__ qkv_wT, const float* __restrict__ qkv_b,
    const float* __restrict__ biasT, u16* __restrict__ att)
{
  // union buffer: phases 1-2 -> sQ[112][40] + sK[112][40]; phases 3-4 -> sP[112][136]
  __shared__ __align__(16) u16 sUni[112 * SVP];   // 30464 B
  __shared__ __align__(16) u16 sVt[32 * SVP];     //  8704 B  [d][kv]
  __shared__ int sReg[112];

  u16* sQ = sUni;
  u16* sK = sUni + 112 * SQP;
  u16* sP = sUni;

  const int tid  = threadIdx.x;
  const int bid  = blockIdx.x;
  const int widx = bid / 3;
  const int head = bid - widx * 3;
  const int ww = widx & 15, hw = (widx >> 4) & 15, tw = widx >> 8;
  const bool bnd = (tw == 7) || (hw == 15) || (ww == 15);
  const int wid = tid >> 6;          // wave 0..3
  const int lane = tid & 63;
  const int g  = lane >> 4;          // lane group 0..3
  const int cl = lane & 15;          // col-in-tile

  // ---- phase 0: zero sVt (pad kv cols must be 0) + region ids
  for (int i = tid; i < 32 * SVP / 2; i += 256) ((u32*)sVt)[i] = 0;
  if (tid < 112) {
    int n = tid;
    int reg = 0;
    if (n < NN) {
      int it = n / 49, r = n - it * 49, ih = r / 7, iw = r - ih * 7;
      int ts = tw * 2 + it, hs = hw * 7 + ih, ws2 = ww * 7 + iw;
      int rt = ts < TT - 2 ? 0 : (ts < TT - 1 ? 1 : 2);
      int rh = hs < HH - 7 ? 0 : (hs < HH - 3 ? 1 : 2);
      int rw = ws2 < WD - 7 ? 0 : (ws2 < WD - 3 ? 1 : 2);
      reg = rt * 9 + rh * 3 + rw;
    }
    sReg[n] = reg;
  }
  __syncthreads();

  // ---- phase 1: QKV slice for this head (A-frags straight from global; D -> sQ/sK/sVt)
  {
    const float scale = 0.17677669529663687f;   // 32^-0.5
    #pragma unroll
    for (int mi = 0; mi < 2; ++mi) {
      const int mt = wid + mi * 4;
      if (mt < 7) {
        const u16* arow = xnw + ((size_t)widx * 112 + mt * 16 + cl) * CC + 8 * g;
        bf16x8 a0 = *(const bf16x8*)(arow);
        bf16x8 a1 = *(const bf16x8*)(arow + 32);
        bf16x8 a2 = *(const bf16x8*)(arow + 64);
        #pragma unroll
        for (int nt = 0; nt < 6; ++nt) {
          const int sec = nt >> 1;                      // 0=Q 1=K 2=V
          const int col = sec * 96 + head * 32 + (nt & 1) * 16 + cl;
          const u16* brow = qkv_wT + (size_t)col * CC + 8 * g;
          f32x4 acc = {0.f, 0.f, 0.f, 0.f};
          acc = MFMA16(a0, *(const bf16x8*)(brow), acc);
          acc = MFMA16(a1, *(const bf16x8*)(brow + 32), acc);
          acc = MFMA16(a2, *(const bf16x8*)(brow + 64), acc);
          const float bias = qkv_b[col];
          #pragma unroll
          for (int r = 0; r < 4; ++r) {
            const int row = mt * 16 + 4 * g + r;
            const float v = acc[r] + bias;
            if (sec == 0)      sQ[row * SQP + (nt & 1) * 16 + cl] = f2bf(v * scale);
            else if (sec == 1) sK[row * SQP + (nt & 1) * 16 + cl] = f2bf(v);
            else               sVt[((nt & 1) * 16 + cl) * SVP + row] = f2bf(v);
          }
        }
      }
    }
  }
  __syncthreads();

  // ---- phase 2: QK^T (MFMA, K=32) + bias/mask + in-register softmax
  float sv[2][7][4];
  #pragma unroll
  for (int mi = 0; mi < 2; ++mi) {
    const int mt = wid + mi * 4;
    if (mt >= 7) continue;
    bf16x8 a = *(const bf16x8*)&sQ[(mt * 16 + cl) * SQP + 8 * g];
    #pragma unroll
    for (int nt = 0; nt < 7; ++nt) {
      bf16x8 b = *(const bf16x8*)&sK[(nt * 16 + cl) * SQP + 8 * g];
      f32x4 acc = {0.f, 0.f, 0.f, 0.f};
      acc = MFMA16(a, b, acc);
      #pragma unroll
      for (int r = 0; r < 4; ++r) sv[mi][nt][r] = acc[r];
    }
    const int q0 = mt * 16 + 4 * g;
    #pragma unroll
    for (int nt = 0; nt < 7; ++nt) {
      const int kv = nt * 16 + cl;
      #pragma unroll
      for (int r = 0; r < 4; ++r) {
        const int q = q0 + r;
        float v = sv[mi][nt][r];
        if (kv < NN) {
          if (q < NN) {
            v += biasT[((head * NN + q)) * NN + kv];
            if (bnd && sReg[q] != sReg[kv]) v -= 100.f;
          }
        } else {
          v = -1e30f;
        }
        sv[mi][nt][r] = v;
      }
    }
    #pragma unroll
    for (int r = 0; r < 4; ++r) {
      float mx = sv[mi][0][r];
      #pragma unroll
      for (int nt = 1; nt < 7; ++nt) mx = fmaxf(mx, sv[mi][nt][r]);
      #pragma unroll
      for (int d = 1; d < 16; d <<= 1) mx = fmaxf(mx, __shfl_xor(mx, d, 64));
      float sm = 0.f;
      #pragma unroll
      for (int nt = 0; nt < 7; ++nt) { float p = __expf(sv[mi][nt][r] - mx); sv[mi][nt][r] = p; sm += p; }
      #pragma unroll
      for (int d = 1; d < 16; d <<= 1) sm += __shfl_xor(sm, d, 64);
      const float inv = 1.f / sm;
      #pragma unroll
      for (int nt = 0; nt < 7; ++nt) sv[mi][nt][r] *= inv;
    }
  }
  __syncthreads();   // all Q/K reads complete before P overwrites the union buffer

  // ---- phase 3: write P (bf16) + zero pad cols 112..127
  #pragma unroll
  for (int mi = 0; mi < 2; ++mi) {
    const int mt = wid + mi * 4;
    if (mt >= 7) continue;
    #pragma unroll
    for (int r = 0; r < 4; ++r) {
      const int q = mt * 16 + 4 * g + r;
      u16* prow = &sP[q * SVP];
      #pragma unroll
      for (int nt = 0; nt < 7; ++nt) prow[nt * 16 + cl] = f2bf(sv[mi][nt][r]);
      prow[112 + cl] = 0;
    }
  }
  __syncthreads();

  // ---- phase 4: PV (MFMA, K=128) + store
  for (int t = wid; t < 14; t += 4) {
    const int mt = t >> 1, ntd = t & 1;
    f32x4 acc = {0.f, 0.f, 0.f, 0.f};
    #pragma unroll
    for (int ks = 0; ks < 4; ++ks) {
      bf16x8 a = *(const bf16x8*)&sP[(mt * 16 + cl) * SVP + ks * 32 + 8 * g];
      bf16x8 b = *(const bf16x8*)&sVt[(ntd * 16 + cl) * SVP + ks * 32 + 8 * g];
      acc = MFMA16(a, b, acc);
    }
    #pragma unroll
    for (int r = 0; r < 4; ++r) {
      const int q = mt * 16 + 4 * g + r;
      if (q < NN)
        att[((size_t)widx * NN + q) * CC + head * 32 + ntd * 16 + cl] = f2bf(acc[r]);
    }
  }
}

// ---------------- K2: fused proj + residual + LN2 + FC1 + GELU + FC2 + residual ----------------
// 2x B-REUSE: 128 threads / 2 waves per 32-token block; wave = nt-half, owns BOTH m-tiles.
// Every proj/FC1/FC2 B-fragment feeds 2 MFMAs (mt0, mt1) -> B L2-traffic halved, MFMA:load 2x.
__global__ __launch_bounds__(128, 4) void pm_kernel(
    const u16* __restrict__ att, const u16* __restrict__ proj_wT, const float* __restrict__ proj_b,
    const float* __restrict__ x,
    const float* __restrict__ g2, const float* __restrict__ b2,
    const u16* __restrict__ fc1_wT, const float* __restrict__ fc1_b,
    const u16* __restrict__ fc2_wT, const float* __restrict__ fc2_b,
    float* __restrict__ out)
{
  __shared__ __align__(16) u16 sH [32 * SHP];    // 25088 B (sA and sX1 alias inside)
  __shared__ __align__(16) u16 sXn[32 * SXP];    //  6656 B
  // total 31744 B -> 5 blocks/CU (10 waves)

  u16* sA  = sH;          // [32][SXP] attention-output tile  (bytes 0..6656)
  u16* sX1 = sH + 4096;   // [32][SX1P] x1 bf16 for LN2       (bytes 8192..14592)

  const int tid  = threadIdx.x;
  const int base = blockIdx.x * 32;              // window-token base
  const int hnt  = tid >> 6;        // wave = nt-half (0..1)
  const int lane = tid & 63, g = lane >> 4, cl = lane & 15;

  // ---- P-1: natural-row indices (both m-tiles) + EARLY x-residual prefetch
  u32 nr[2][4];
  #pragma unroll
  for (int mt = 0; mt < 2; ++mt) {
    #pragma unroll
    for (int r = 0; r < 4; ++r) {
      int tok = base + mt * 16 + 4 * g + r;
      int widx = tok / NN, n = tok - widx * NN;
      int ww = widx & 15, hw = (widx >> 4) & 15, tw = widx >> 8;
      int it = n / 49, rr = n - it * 49, ih = rr / 7, iw = rr - ih * 7;
      int t = tw * 2 + it + 1; if (t >= TT) t -= TT;
      int h = hw * 7 + ih + 3; if (h >= HH) h -= HH;
      int w = ww * 7 + iw + 3; if (w >= WD) w -= WD;
      nr[mt][r] = (u32)((t * HH + h) * WD + w);
    }
  }
  float xres[3][2][4];
  #pragma unroll
  for (int j = 0; j < 3; ++j) {
    const int col = (hnt * 3 + j) * 16 + cl;
    #pragma unroll
    for (int mt = 0; mt < 2; ++mt)
      #pragma unroll
      for (int r = 0; r < 4; ++r)
        xres[j][mt][r] = x[(size_t)nr[mt][r] * CC + col];
  }

  // ---- P0: att tile load -> sA (128 threads, 384 uint4)
  for (int e = tid; e < 32 * 12; e += 128) {
    int tok = e / 12, kb = e - tok * 12;
    *(uint4*)&sA[tok * SXP + kb * 8] =
        ((const uint4*)att)[(size_t)(base + tok) * 12 + kb];
  }
  __syncthreads();

  // ---- P1: proj GEMM [32x96]@[96x96]: B loaded once per nt, used for BOTH m-tiles
  float x1v[3][2][4];
  {
    bf16x8 a[2][3];
    #pragma unroll
    for (int mt = 0; mt < 2; ++mt) {
      const u16* aRow = &sA[(mt * 16 + cl) * SXP + 8 * g];
      a[mt][0] = *(const bf16x8*)(aRow);
      a[mt][1] = *(const bf16x8*)(aRow + 32);
      a[mt][2] = *(const bf16x8*)(aRow + 64);
    }
    #pragma unroll
    for (int j = 0; j < 3; ++j) {
      const int nt = hnt * 3 + j;
      const u16* bRow = proj_wT + (nt * 16 + cl) * CC + 8 * g;
      bf16x8 b0 = *(const bf16x8*)(bRow);
      bf16x8 b1 = *(const bf16x8*)(bRow + 32);
      bf16x8 b2 = *(const bf16x8*)(bRow + 64);
      const float bc = proj_b[nt * 16 + cl];
      #pragma unroll
      for (int mt = 0; mt < 2; ++mt) {
        f32x4 acc = {0.f, 0.f, 0.f, 0.f};
        acc = MFMA16(a[mt][0], b0, acc);
        acc = MFMA16(a[mt][1], b1, acc);
        acc = MFMA16(a[mt][2], b2, acc);
        #pragma unroll
        for (int r = 0; r < 4; ++r) {
          const int row = mt * 16 + 4 * g + r;
          const float v = acc[r] + bc + xres[j][mt][r];
          x1v[j][mt][r] = v;
          sX1[row * SX1P + nt * 16 + cl] = f2bf(v);
        }
      }
    }
  }
  __syncthreads();   // sA reads + sX1 writes complete

  // ---- P2: LN2 from sX1 (bf16): token = tid>>2 (32), sub = tid&3 (24 ch); 4-lane shfl
  {
    const int tok = tid >> 2, sub = tid & 3;
    const u16* p = &sX1[tok * SX1P + sub * 24];
    float v[24];
    #pragma unroll
    for (int k = 0; k < 12; ++k) {
      u32 u = *(const u32*)(p + 2 * k);
      v[2 * k] = bflo(u); v[2 * k + 1] = bfhi(u);
    }
    float sm = 0.f;
    #pragma unroll
    for (int i = 0; i < 24; ++i) sm += v[i];
    sm += __shfl_xor(sm, 1, 64);
    sm += __shfl_xor(sm, 2, 64);
    float mu = sm * (1.f / CC);
    float sq = 0.f;
    #pragma unroll
    for (int i = 0; i < 24; ++i) { float d = v[i] - mu; sq += d * d; }
    sq += __shfl_xor(sq, 1, 64);
    sq += __shfl_xor(sq, 2, 64);
    float inv = rsqrtf(sq * (1.f / CC) + 1e-5f);
    u16 o[24];
    #pragma unroll
    for (int i = 0; i < 24; ++i) {
      int c = sub * 24 + i;
      o[i] = f2bf((v[i] - mu) * inv * g2[c] + b2[c]);
    }
    u16* dst = &sXn[tok * SXP + sub * 24];
    *(uint4*)(dst)      = *(const uint4*)(o);
    *(uint4*)(dst + 8)  = *(const uint4*)(o + 8);
    *(uint4*)(dst + 16) = *(const uint4*)(o + 16);
  }
  __syncthreads();   // sX1 reads complete; sH free for P3

  // ---- P3: FC1 [32x96]@[96x384] + GELU -> sH; B once per nt, 2 MFMA-triples (mt0,mt1)
  {
    bf16x8 a[2][3];
    #pragma unroll
    for (int mt = 0; mt < 2; ++mt) {
      const u16* aXn = &sXn[(mt * 16 + cl) * SXP + 8 * g];
      a[mt][0] = *(const bf16x8*)(aXn);
      a[mt][1] = *(const bf16x8*)(aXn + 32);
      a[mt][2] = *(const bf16x8*)(aXn + 64);
    }
    const int nt0 = hnt * 12;
    const u16* bPtr = fc1_wT + ((size_t)(nt0 * 16 + cl)) * CC + 8 * g;
    bf16x8 b0 = *(const bf16x8*)(bPtr);
    bf16x8 b1 = *(const bf16x8*)(bPtr + 32);
    bf16x8 b2 = *(const bf16x8*)(bPtr + 64);
    #pragma unroll
    for (int j = 0; j < 12; ++j) {
      bf16x8 c0 = b0, c1 = b1, c2 = b2;
      if (j < 11) {                       // prefetch next nt
        bPtr += 16 * CC;
        b0 = *(const bf16x8*)(bPtr);
        b1 = *(const bf16x8*)(bPtr + 32);
        b2 = *(const bf16x8*)(bPtr + 64);
      }
      const int nt = nt0 + j;
      const float bj = fc1_b[nt * 16 + cl];
      #pragma unroll
      for (int mt = 0; mt < 2; ++mt) {
        f32x4 acc = {0.f, 0.f, 0.f, 0.f};
        acc = MFMA16(a[mt][0], c0, acc);
        acc = MFMA16(a[mt][1], c1, acc);
        acc = MFMA16(a[mt][2], c2, acc);
        #pragma unroll
        for (int r = 0; r < 4; ++r) {
          float v = acc[r] + bj;
          // tanh-GELU: v*e/(e+1), e = exp(v*(1.59576912 + 0.07135481*v^2))
          float p2 = v * v;
          float aa = v * fmaf(0.07135481f, p2, 1.59576912f);
          float e  = __expf(aa);
          float gl = v * e * __builtin_amdgcn_rcpf(e + 1.f);
          sH[(mt * 16 + 4 * g + r) * SHP + nt * 16 + cl] = f2bf(gl);
        }
      }
    }
  }
  __syncthreads();

  // ---- P4: FC2 [32x384]@[384x96] in 4 k-quarters; B once per (nt,q), 2 MFMAs each
  {
    f32x4 acc2[3][2];
    #pragma unroll
    for (int j = 0; j < 3; ++j)
      #pragma unroll
      for (int mt = 0; mt < 2; ++mt) { f32x4 z = {0.f, 0.f, 0.f, 0.f}; acc2[j][mt] = z; }

    #pragma unroll
    for (int q = 0; q < 4; ++q) {
      bf16x8 a[2][3];
      #pragma unroll
      for (int mt = 0; mt < 2; ++mt) {
        const u16* aBase = &sH[(mt * 16 + cl) * SHP + q * 96 + 8 * g];
        a[mt][0] = *(const bf16x8*)(aBase);
        a[mt][1] = *(const bf16x8*)(aBase + 32);
        a[mt][2] = *(const bf16x8*)(aBase + 64);
      }
      #pragma unroll
      for (int j = 0; j < 3; ++j) {
        const int nt = hnt * 3 + j;
        const u16* bBase = fc2_wT + (size_t)(nt * 16 + cl) * MLPH + q * 96 + 8 * g;
        bf16x8 b0 = *(const bf16x8*)(bBase);
        bf16x8 b1 = *(const bf16x8*)(bBase + 32);
        bf16x8 b2 = *(const bf16x8*)(bBase + 64);
        #pragma unroll
        for (int mt = 0; mt < 2; ++mt) {
          acc2[j][mt] = MFMA16(a[mt][0], b0, acc2[j][mt]);
          acc2[j][mt] = MFMA16(a[mt][1], b1, acc2[j][mt]);
          acc2[j][mt] = MFMA16(a[mt][2], b2, acc2[j][mt]);
        }
      }
    }
    #pragma unroll
    for (int j = 0; j < 3; ++j) {
      const int nt = hnt * 3 + j;
      const float bc = fc2_b[nt * 16 + cl];
      #pragma unroll
      for (int mt = 0; mt < 2; ++mt)
        #pragma unroll
        for (int r = 0; r < 4; ++r)
          out[(size_t)nr[mt][r] * CC + nt * 16 + cl] = x1v[j][mt][r] + acc2[j][mt][r] + bc;
    }
  }
}

extern "C" void kernel_launch(void* const* d_in, const int* in_sizes, int n_in,
                              void* d_out, int out_size, void* d_ws, size_t ws_size,
                              hipStream_t stream) {
  const float* x      = (const float*)d_in[0];
  const float* g1     = (const float*)d_in[1];
  const float* b1     = (const float*)d_in[2];
  const float* qkv_w  = (const float*)d_in[3];
  const float* qkv_b  = (const float*)d_in[4];
  const float* rpb    = (const float*)d_in[5];
  const float* proj_w = (const float*)d_in[6];
  const float* proj_b = (const float*)d_in[7];
  const float* g2     = (const float*)d_in[8];
  const float* b2     = (const float*)d_in[9];
  const float* fc1_w  = (const float*)d_in[10];
  const float* fc1_b  = (const float*)d_in[11];
  const float* fc2_w  = (const float*)d_in[12];
  const float* fc2_b  = (const float*)d_in[13];

  char* ws = (char*)d_ws;
  u16*   att    = (u16*)ws;                                   // NTOK*96 bf16 = 38.5 MB
  u16*   xnw    = (u16*)(ws + (size_t)NTOK * CC * 2);         // NWIN*112*96 bf16 = 44 MB
  char*  wtail  = ws + (size_t)NTOK * CC * 2 + (size_t)NWIN * 112 * CC * 2;
  float* biasT  = (float*)wtail;                              // 115248 B
  u16*   qkv_wT = (u16*)(wtail + 115248);                     // 55296 B
  u16*   proj_wT= (u16*)(wtail + 115248 + 55296);             // 18432 B
  u16*   fc1_wT = (u16*)(wtail + 115248 + 55296 + 18432);     // 73728 B
  u16*   fc2_wT = (u16*)(wtail + 115248 + 55296 + 18432 + 73728); // 73728 B

  wprep_kernel<<<(27648 + 9216 + 36864 + 36864 + 255) / 256, 256, 0, stream>>>(
      qkv_w, proj_w, fc1_w, fc2_w, qkv_wT, proj_wT, fc1_wT, fc2_wT);
  bias_kernel<<<(NHEADS * NN * NN + 255) / 256, 256, 0, stream>>>(rpb, biasT);
  ln1_kernel<<<NWIN * 112 / 64, 256, 0, stream>>>(x, g1, b1, xnw);
  attn_kernel<<<NWIN * NHEADS, 256, 0, stream>>>(xnw, qkv_wT, qkv_b, biasT, att);
  pm_kernel<<<NTOK / 32, 128, 0, stream>>>(att, proj_wT, proj_b, x, g2, b2,
                                           fc1_wT, fc1_b, fc2_wT, fc2_b, (float*)d_out);
}

// Round 16
// 273.441 us; speedup vs baseline: 1.3134x; 1.0168x over previous
//
#include <hip/hip_runtime.h>
#include <math.h>

#define TT 16
#define HH 112
#define WD 112
#define CC 96
#define NHEADS 3
#define HD 32
#define NN 98          // window tokens 2*7*7
#define NWIN 2048      // 8*16*16
#define NTOK 200704    // T*H*W == NWIN*NN
#define MLPH 384
#define SXP 104        // row stride (bf16) LDS tiles (208B rows, 16B aligned)
#define SQP 40         // row stride (bf16) per-head sQ/sK
#define SVP 136        // row stride (bf16) sVt/sP
#define SHP 392        // row stride (bf16) sH full (384 cols + 8 pad)
#define SX1P 100       // row stride (bf16) sX1

typedef unsigned int  u32;
typedef unsigned short u16;
typedef float f32x4 __attribute__((ext_vector_type(4)));
typedef short bf16x8 __attribute__((ext_vector_type(8)));

__device__ inline u16 f2bf(float f) {
  u32 u = __float_as_uint(f);
  u += 0x7fffu + ((u >> 16) & 1u);
  return (u16)(u >> 16);
}
__device__ inline float bflo(u32 u) { return __uint_as_float(u << 16); }
__device__ inline float bfhi(u32 u) { return __uint_as_float(u & 0xffff0000u); }

#define MFMA16(a, b, c) __builtin_amdgcn_mfma_f32_16x16x32_bf16((a), (b), (c), 0, 0, 0)

// ---------------- K0a: transpose all weights to bf16 col-major ----------------
__global__ __launch_bounds__(256) void wprep_kernel(
    const float* __restrict__ qkv_w, const float* __restrict__ proj_w,
    const float* __restrict__ fc1_w, const float* __restrict__ fc2_w,
    u16* __restrict__ qkv_wT, u16* __restrict__ proj_wT,
    u16* __restrict__ fc1_wT, u16* __restrict__ fc2_wT) {
  int idx = blockIdx.x * 256 + threadIdx.x;
  if (idx < 27648) {                       // qkv_wT[col][c]
    int col = idx / CC, c = idx - col * CC;
    qkv_wT[idx] = f2bf(qkv_w[c * (3 * CC) + col]);
    return;
  }
  idx -= 27648;
  if (idx < 9216) {                        // proj_wT[col][c]
    int col = idx / CC, c = idx - col * CC;
    proj_wT[idx] = f2bf(proj_w[c * CC + col]);
    return;
  }
  idx -= 9216;
  if (idx < 36864) {                       // fc1_wT[j][c]
    int j = idx / CC, c = idx - j * CC;
    fc1_wT[idx] = f2bf(fc1_w[c * MLPH + j]);
    return;
  }
  idx -= 36864;
  if (idx < 36864) {                       // fc2_wT[c][j]
    int c = idx / MLPH, j = idx - c * MLPH;
    fc2_wT[idx] = f2bf(fc2_w[j * CC + c]);
  }
}

// ---------------- K0b: biasT[head][q][kv] = rpb[ridx(q,kv)*3+head] ----------------
__global__ __launch_bounds__(256) void bias_kernel(const float* __restrict__ rpb,
                                                   float* __restrict__ biasT) {
  int idx = blockIdx.x * 256 + threadIdx.x;
  if (idx >= NHEADS * NN * NN) return;
  int head = idx / (NN * NN);
  int r = idx - head * NN * NN;
  int q = r / NN, kv = r - q * NN;
  int itq = q / 49, rq = q - itq * 49, ihq = rq / 7, iwq = rq - ihq * 7;
  int itk = kv / 49, rk = kv - itk * 49, ihk = rk / 7, iwk = rk - ihk * 7;
  int ridx = (itq - itk + 1) * 169 + (ihq - ihk + 6) * 13 + (iwq - iwk + 6);
  biasT[idx] = rpb[ridx * NHEADS + head];
}

// ---------------- K0c: LN1 + shift-roll + window gather -> xnw[widx][112][96] bf16 ----------------
__global__ __launch_bounds__(256) void ln1_kernel(
    const float* __restrict__ x, const float* __restrict__ g1, const float* __restrict__ b1,
    u16* __restrict__ xnw)
{
  const int tid = threadIdx.x;
  const int row = blockIdx.x * 64 + (tid >> 2);   // 0 .. NWIN*112-1
  const int qd = tid & 3;                          // quarter: 24 channels
  const int widx = row / 112;
  const int n = row - widx * 112;
  u16* dst = xnw + (size_t)row * CC + qd * 24;
  if (n >= NN) {                                   // pad row -> zeros
    uint4 z = {0u, 0u, 0u, 0u};
    *(uint4*)(dst) = z; *(uint4*)(dst + 8) = z; *(uint4*)(dst + 16) = z;
    return;
  }
  int it = n / 49, r = n - it * 49, ih = r / 7, iw = r - ih * 7;
  int ww = widx & 15, hw = (widx >> 4) & 15, tw = widx >> 8;
  int t = tw * 2 + it + 1; if (t >= TT) t -= TT;
  int h = hw * 7 + ih + 3; if (h >= HH) h -= HH;
  int w = ww * 7 + iw + 3; if (w >= WD) w -= WD;
  const float* src = x + ((size_t)(t * HH + h) * WD + w) * CC + qd * 24;
  float v[24];
  #pragma unroll
  for (int i = 0; i < 24; i += 4) {
    float4 f = *(const float4*)(src + i);
    v[i] = f.x; v[i + 1] = f.y; v[i + 2] = f.z; v[i + 3] = f.w;
  }
  float sm = 0.f;
  #pragma unroll
  for (int i = 0; i < 24; ++i) sm += v[i];
  sm += __shfl_xor(sm, 1, 64);
  sm += __shfl_xor(sm, 2, 64);
  float mu = sm * (1.f / CC);
  float sq = 0.f;
  #pragma unroll
  for (int i = 0; i < 24; ++i) { float d = v[i] - mu; sq += d * d; }
  sq += __shfl_xor(sq, 1, 64);
  sq += __shfl_xor(sq, 2, 64);
  float inv = rsqrtf(sq * (1.f / CC) + 1e-5f);
  u16 o[24];
  #pragma unroll
  for (int i = 0; i < 24; ++i) {
    int c = qd * 24 + i;
    o[i] = f2bf((v[i] - mu) * inv * g1[c] + b1[c]);
  }
  *(uint4*)(dst)      = *(const uint4*)(o);
  *(uint4*)(dst + 8)  = *(const uint4*)(o + 8);
  *(uint4*)(dst + 16) = *(const uint4*)(o + 16);
}

// ---------------- K1: per-(window,head) QKV + attention (MFMA) ----------------
// r15 lever applied: phase-1 B-frags loaded ONCE per nt (feed both m-tiles);
// A-frags prefetched from global at kernel top (latency hides under phase 0).
__global__ __launch_bounds__(256, 4) void attn_kernel(
    const u16* __restrict__ xnw, const u16* __restrict__ qkv_wT, const float* __restrict__ qkv_b,
    const float* __restrict__ biasT, u16* __restrict__ att)
{
  // union buffer: phases 1-2 -> sQ[112][40] + sK[112][40]; phases 3-4 -> sP[112][136]
  __shared__ __align__(16) u16 sUni[112 * SVP];   // 30464 B
  __shared__ __align__(16) u16 sVt[32 * SVP];     //  8704 B  [d][kv]
  __shared__ int sReg[112];

  u16* sQ = sUni;
  u16* sK = sUni + 112 * SQP;
  u16* sP = sUni;

  const int tid  = threadIdx.x;
  const int bid  = blockIdx.x;
  const int widx = bid / 3;
  const int head = bid - widx * 3;
  const int ww = widx & 15, hw = (widx >> 4) & 15, tw = widx >> 8;
  const bool bnd = (tw == 7) || (hw == 15) || (ww == 15);
  const int wid = tid >> 6;          // wave 0..3
  const int lane = tid & 63;
  const int g  = lane >> 4;          // lane group 0..3
  const int cl = lane & 15;          // col-in-tile
  const int mt1ok = (wid + 4) < 7;   // wave 3 has only one m-tile

  // ---- EARLY: prefetch phase-1 A-frags from global (consumed after phase-0 barrier)
  bf16x8 xa[2][3];
  {
    const u16* arow0 = xnw + ((size_t)widx * 112 + wid * 16 + cl) * CC + 8 * g;
    xa[0][0] = *(const bf16x8*)(arow0);
    xa[0][1] = *(const bf16x8*)(arow0 + 32);
    xa[0][2] = *(const bf16x8*)(arow0 + 64);
    const int mtb = mt1ok ? (wid + 4) : wid;   // clamp (wave3: harmless reload)
    const u16* arow1 = xnw + ((size_t)widx * 112 + mtb * 16 + cl) * CC + 8 * g;
    xa[1][0] = *(const bf16x8*)(arow1);
    xa[1][1] = *(const bf16x8*)(arow1 + 32);
    xa[1][2] = *(const bf16x8*)(arow1 + 64);
  }

  // ---- phase 0: zero sVt (pad kv cols must be 0) + region ids
  for (int i = tid; i < 32 * SVP / 2; i += 256) ((u32*)sVt)[i] = 0;
  if (tid < 112) {
    int n = tid;
    int reg = 0;
    if (n < NN) {
      int it = n / 49, r = n - it * 49, ih = r / 7, iw = r - ih * 7;
      int ts = tw * 2 + it, hs = hw * 7 + ih, ws2 = ww * 7 + iw;
      int rt = ts < TT - 2 ? 0 : (ts < TT - 1 ? 1 : 2);
      int rh = hs < HH - 7 ? 0 : (hs < HH - 3 ? 1 : 2);
      int rw = ws2 < WD - 7 ? 0 : (ws2 < WD - 3 ? 1 : 2);
      reg = rt * 9 + rh * 3 + rw;
    }
    sReg[n] = reg;
  }
  __syncthreads();

  // ---- phase 1: QKV slice (nt-outer: B loaded once, feeds both m-tiles)
  {
    const float scale = 0.17677669529663687f;   // 32^-0.5
    #pragma unroll
    for (int nt = 0; nt < 6; ++nt) {
      const int sec = nt >> 1;                      // 0=Q 1=K 2=V
      const int col = sec * 96 + head * 32 + (nt & 1) * 16 + cl;
      const u16* brow = qkv_wT + (size_t)col * CC + 8 * g;
      bf16x8 b0 = *(const bf16x8*)(brow);
      bf16x8 b1 = *(const bf16x8*)(brow + 32);
      bf16x8 b2 = *(const bf16x8*)(brow + 64);
      const float bias = qkv_b[col];
      #pragma unroll
      for (int mi = 0; mi < 2; ++mi) {
        const int mt = wid + mi * 4;
        if (mi == 1 && !mt1ok) continue;
        f32x4 acc = {0.f, 0.f, 0.f, 0.f};
        acc = MFMA16(xa[mi][0], b0, acc);
        acc = MFMA16(xa[mi][1], b1, acc);
        acc = MFMA16(xa[mi][2], b2, acc);
        #pragma unroll
        for (int r = 0; r < 4; ++r) {
          const int row = mt * 16 + 4 * g + r;
          const float v = acc[r] + bias;
          if (sec == 0)      sQ[row * SQP + (nt & 1) * 16 + cl] = f2bf(v * scale);
          else if (sec == 1) sK[row * SQP + (nt & 1) * 16 + cl] = f2bf(v);
          else               sVt[((nt & 1) * 16 + cl) * SVP + row] = f2bf(v);
        }
      }
    }
  }
  __syncthreads();

  // ---- phase 2: QK^T (MFMA, K=32) + bias/mask + in-register softmax
  float sv[2][7][4];
  #pragma unroll
  for (int mi = 0; mi < 2; ++mi) {
    const int mt = wid + mi * 4;
    if (mt >= 7) continue;
    bf16x8 a = *(const bf16x8*)&sQ[(mt * 16 + cl) * SQP + 8 * g];
    #pragma unroll
    for (int nt = 0; nt < 7; ++nt) {
      bf16x8 b = *(const bf16x8*)&sK[(nt * 16 + cl) * SQP + 8 * g];
      f32x4 acc = {0.f, 0.f, 0.f, 0.f};
      acc = MFMA16(a, b, acc);
      #pragma unroll
      for (int r = 0; r < 4; ++r) sv[mi][nt][r] = acc[r];
    }
    const int q0 = mt * 16 + 4 * g;
    #pragma unroll
    for (int nt = 0; nt < 7; ++nt) {
      const int kv = nt * 16 + cl;
      #pragma unroll
      for (int r = 0; r < 4; ++r) {
        const int q = q0 + r;
        float v = sv[mi][nt][r];
        if (kv < NN) {
          if (q < NN) {
            v += biasT[((head * NN + q)) * NN + kv];
            if (bnd && sReg[q] != sReg[kv]) v -= 100.f;
          }
        } else {
          v = -1e30f;
        }
        sv[mi][nt][r] = v;
      }
    }
    #pragma unroll
    for (int r = 0; r < 4; ++r) {
      float mx = sv[mi][0][r];
      #pragma unroll
      for (int nt = 1; nt < 7; ++nt) mx = fmaxf(mx, sv[mi][nt][r]);
      #pragma unroll
      for (int d = 1; d < 16; d <<= 1) mx = fmaxf(mx, __shfl_xor(mx, d, 64));
      float sm = 0.f;
      #pragma unroll
      for (int nt = 0; nt < 7; ++nt) { float p = __expf(sv[mi][nt][r] - mx); sv[mi][nt][r] = p; sm += p; }
      #pragma unroll
      for (int d = 1; d < 16; d <<= 1) sm += __shfl_xor(sm, d, 64);
      const float inv = 1.f / sm;
      #pragma unroll
      for (int nt = 0; nt < 7; ++nt) sv[mi][nt][r] *= inv;
    }
  }
  __syncthreads();   // all Q/K reads complete before P overwrites the union buffer

  // ---- phase 3: write P (bf16) + zero pad cols 112..127
  #pragma unroll
  for (int mi = 0; mi < 2; ++mi) {
    const int mt = wid + mi * 4;
    if (mt >= 7) continue;
    #pragma unroll
    for (int r = 0; r < 4; ++r) {
      const int q = mt * 16 + 4 * g + r;
      u16* prow = &sP[q * SVP];
      #pragma unroll
      for (int nt = 0; nt < 7; ++nt) prow[nt * 16 + cl] = f2bf(sv[mi][nt][r]);
      prow[112 + cl] = 0;
    }
  }
  __syncthreads();

  // ---- phase 4: PV (MFMA, K=128) + store
  for (int t = wid; t < 14; t += 4) {
    const int mt = t >> 1, ntd = t & 1;
    f32x4 acc = {0.f, 0.f, 0.f, 0.f};
    #pragma unroll
    for (int ks = 0; ks < 4; ++ks) {
      bf16x8 a = *(const bf16x8*)&sP[(mt * 16 + cl) * SVP + ks * 32 + 8 * g];
      bf16x8 b = *(const bf16x8*)&sVt[(ntd * 16 + cl) * SVP + ks * 32 + 8 * g];
      acc = MFMA16(a, b, acc);
    }
    #pragma unroll
    for (int r = 0; r < 4; ++r) {
      const int q = mt * 16 + 4 * g + r;
      if (q < NN)
        att[((size_t)widx * NN + q) * CC + head * 32 + ntd * 16 + cl] = f2bf(acc[r]);
    }
  }
}

// ---------------- K2: fused proj + residual + LN2 + FC1 + GELU + FC2 + residual ----------------
// 2x B-REUSE: 128 threads / 2 waves per 32-token block; wave = nt-half, owns BOTH m-tiles.
// Every proj/FC1/FC2 B-fragment feeds 2 MFMAs (mt0, mt1) -> B L2-traffic halved, MFMA:load 2x.
__global__ __launch_bounds__(128, 4) void pm_kernel(
    const u16* __restrict__ att, const u16* __restrict__ proj_wT, const float* __restrict__ proj_b,
    const float* __restrict__ x,
    const float* __restrict__ g2, const float* __restrict__ b2,
    const u16* __restrict__ fc1_wT, const float* __restrict__ fc1_b,
    const u16* __restrict__ fc2_wT, const float* __restrict__ fc2_b,
    float* __restrict__ out)
{
  __shared__ __align__(16) u16 sH [32 * SHP];    // 25088 B (sA and sX1 alias inside)
  __shared__ __align__(16) u16 sXn[32 * SXP];    //  6656 B
  // total 31744 B -> 5 blocks/CU (10 waves)

  u16* sA  = sH;          // [32][SXP] attention-output tile  (bytes 0..6656)
  u16* sX1 = sH + 4096;   // [32][SX1P] x1 bf16 for LN2       (bytes 8192..14592)

  const int tid  = threadIdx.x;
  const int base = blockIdx.x * 32;              // window-token base
  const int hnt  = tid >> 6;        // wave = nt-half (0..1)
  const int lane = tid & 63, g = lane >> 4, cl = lane & 15;

  // ---- P-1: natural-row indices (both m-tiles) + EARLY x-residual prefetch
  u32 nr[2][4];
  #pragma unroll
  for (int mt = 0; mt < 2; ++mt) {
    #pragma unroll
    for (int r = 0; r < 4; ++r) {
      int tok = base + mt * 16 + 4 * g + r;
      int widx = tok / NN, n = tok - widx * NN;
      int ww = widx & 15, hw = (widx >> 4) & 15, tw = widx >> 8;
      int it = n / 49, rr = n - it * 49, ih = rr / 7, iw = rr - ih * 7;
      int t = tw * 2 + it + 1; if (t >= TT) t -= TT;
      int h = hw * 7 + ih + 3; if (h >= HH) h -= HH;
      int w = ww * 7 + iw + 3; if (w >= WD) w -= WD;
      nr[mt][r] = (u32)((t * HH + h) * WD + w);
    }
  }
  float xres[3][2][4];
  #pragma unroll
  for (int j = 0; j < 3; ++j) {
    const int col = (hnt * 3 + j) * 16 + cl;
    #pragma unroll
    for (int mt = 0; mt < 2; ++mt)
      #pragma unroll
      for (int r = 0; r < 4; ++r)
        xres[j][mt][r] = x[(size_t)nr[mt][r] * CC + col];
  }

  // ---- P0: att tile load -> sA (128 threads, 384 uint4)
  for (int e = tid; e < 32 * 12; e += 128) {
    int tok = e / 12, kb = e - tok * 12;
    *(uint4*)&sA[tok * SXP + kb * 8] =
        ((const uint4*)att)[(size_t)(base + tok) * 12 + kb];
  }
  __syncthreads();

  // ---- P1: proj GEMM [32x96]@[96x96]: B loaded once per nt, used for BOTH m-tiles
  float x1v[3][2][4];
  {
    bf16x8 a[2][3];
    #pragma unroll
    for (int mt = 0; mt < 2; ++mt) {
      const u16* aRow = &sA[(mt * 16 + cl) * SXP + 8 * g];
      a[mt][0] = *(const bf16x8*)(aRow);
      a[mt][1] = *(const bf16x8*)(aRow + 32);
      a[mt][2] = *(const bf16x8*)(aRow + 64);
    }
    #pragma unroll
    for (int j = 0; j < 3; ++j) {
      const int nt = hnt * 3 + j;
      const u16* bRow = proj_wT + (nt * 16 + cl) * CC + 8 * g;
      bf16x8 b0 = *(const bf16x8*)(bRow);
      bf16x8 b1 = *(const bf16x8*)(bRow + 32);
      bf16x8 b2 = *(const bf16x8*)(bRow + 64);
      const float bc = proj_b[nt * 16 + cl];
      #pragma unroll
      for (int mt = 0; mt < 2; ++mt) {
        f32x4 acc = {0.f, 0.f, 0.f, 0.f};
        acc = MFMA16(a[mt][0], b0, acc);
        acc = MFMA16(a[mt][1], b1, acc);
        acc = MFMA16(a[mt][2], b2, acc);
        #pragma unroll
        for (int r = 0; r < 4; ++r) {
          const int row = mt * 16 + 4 * g + r;
          const float v = acc[r] + bc + xres[j][mt][r];
          x1v[j][mt][r] = v;
          sX1[row * SX1P + nt * 16 + cl] = f2bf(v);
        }
      }
    }
  }
  __syncthreads();   // sA reads + sX1 writes complete

  // ---- P2: LN2 from sX1 (bf16): token = tid>>2 (32), sub = tid&3 (24 ch); 4-lane shfl
  {
    const int tok = tid >> 2, sub = tid & 3;
    const u16* p = &sX1[tok * SX1P + sub * 24];
    float v[24];
    #pragma unroll
    for (int k = 0; k < 12; ++k) {
      u32 u = *(const u32*)(p + 2 * k);
      v[2 * k] = bflo(u); v[2 * k + 1] = bfhi(u);
    }
    float sm = 0.f;
    #pragma unroll
    for (int i = 0; i < 24; ++i) sm += v[i];
    sm += __shfl_xor(sm, 1, 64);
    sm += __shfl_xor(sm, 2, 64);
    float mu = sm * (1.f / CC);
    float sq = 0.f;
    #pragma unroll
    for (int i = 0; i < 24; ++i) { float d = v[i] - mu; sq += d * d; }
    sq += __shfl_xor(sq, 1, 64);
    sq += __shfl_xor(sq, 2, 64);
    float inv = rsqrtf(sq * (1.f / CC) + 1e-5f);
    u16 o[24];
    #pragma unroll
    for (int i = 0; i < 24; ++i) {
      int c = sub * 24 + i;
      o[i] = f2bf((v[i] - mu) * inv * g2[c] + b2[c]);
    }
    u16* dst = &sXn[tok * SXP + sub * 24];
    *(uint4*)(dst)      = *(const uint4*)(o);
    *(uint4*)(dst + 8)  = *(const uint4*)(o + 8);
    *(uint4*)(dst + 16) = *(const uint4*)(o + 16);
  }
  __syncthreads();   // sX1 reads complete; sH free for P3

  // ---- P3: FC1 [32x96]@[96x384] + GELU -> sH; B once per nt, 2 MFMA-triples (mt0,mt1)
  {
    bf16x8 a[2][3];
    #pragma unroll
    for (int mt = 0; mt < 2; ++mt) {
      const u16* aXn = &sXn[(mt * 16 + cl) * SXP + 8 * g];
      a[mt][0] = *(const bf16x8*)(aXn);
      a[mt][1] = *(const bf16x8*)(aXn + 32);
      a[mt][2] = *(const bf16x8*)(aXn + 64);
    }
    const int nt0 = hnt * 12;
    const u16* bPtr = fc1_wT + ((size_t)(nt0 * 16 + cl)) * CC + 8 * g;
    bf16x8 b0 = *(const bf16x8*)(bPtr);
    bf16x8 b1 = *(const bf16x8*)(bPtr + 32);
    bf16x8 b2 = *(const bf16x8*)(bPtr + 64);
    #pragma unroll
    for (int j = 0; j < 12; ++j) {
      bf16x8 c0 = b0, c1 = b1, c2 = b2;
      if (j < 11) {                       // prefetch next nt
        bPtr += 16 * CC;
        b0 = *(const bf16x8*)(bPtr);
        b1 = *(const bf16x8*)(bPtr + 32);
        b2 = *(const bf16x8*)(bPtr + 64);
      }
      const int nt = nt0 + j;
      const float bj = fc1_b[nt * 16 + cl];
      #pragma unroll
      for (int mt = 0; mt < 2; ++mt) {
        f32x4 acc = {0.f, 0.f, 0.f, 0.f};
        acc = MFMA16(a[mt][0], c0, acc);
        acc = MFMA16(a[mt][1], c1, acc);
        acc = MFMA16(a[mt][2], c2, acc);
        #pragma unroll
        for (int r = 0; r < 4; ++r) {
          float v = acc[r] + bj;
          // tanh-GELU: v*e/(e+1), e = exp(v*(1.59576912 + 0.07135481*v^2))
          float p2 = v * v;
          float aa = v * fmaf(0.07135481f, p2, 1.59576912f);
          float e  = __expf(aa);
          float gl = v * e * __builtin_amdgcn_rcpf(e + 1.f);
          sH[(mt * 16 + 4 * g + r) * SHP + nt * 16 + cl] = f2bf(gl);
        }
      }
    }
  }
  __syncthreads();

  // ---- P4: FC2 [32x384]@[384x96] in 4 k-quarters; B once per (nt,q), 2 MFMAs each
  {
    f32x4 acc2[3][2];
    #pragma unroll
    for (int j = 0; j < 3; ++j)
      #pragma unroll
      for (int mt = 0; mt < 2; ++mt) { f32x4 z = {0.f, 0.f, 0.f, 0.f}; acc2[j][mt] = z; }

    #pragma unroll
    for (int q = 0; q < 4; ++q) {
      bf16x8 a[2][3];
      #pragma unroll
      for (int mt = 0; mt < 2; ++mt) {
        const u16* aBase = &sH[(mt * 16 + cl) * SHP + q * 96 + 8 * g];
        a[mt][0] = *(const bf16x8*)(aBase);
        a[mt][1] = *(const bf16x8*)(aBase + 32);
        a[mt][2] = *(const bf16x8*)(aBase + 64);
      }
      #pragma unroll
      for (int j = 0; j < 3; ++j) {
        const int nt = hnt * 3 + j;
        const u16* bBase = fc2_wT + (size_t)(nt * 16 + cl) * MLPH + q * 96 + 8 * g;
        bf16x8 b0 = *(const bf16x8*)(bBase);
        bf16x8 b1 = *(const bf16x8*)(bBase + 32);
        bf16x8 b2 = *(const bf16x8*)(bBase + 64);
        #pragma unroll
        for (int mt = 0; mt < 2; ++mt) {
          acc2[j][mt] = MFMA16(a[mt][0], b0, acc2[j][mt]);
          acc2[j][mt] = MFMA16(a[mt][1], b1, acc2[j][mt]);
          acc2[j][mt] = MFMA16(a[mt][2], b2, acc2[j][mt]);
        }
      }
    }
    #pragma unroll
    for (int j = 0; j < 3; ++j) {
      const int nt = hnt * 3 + j;
      const float bc = fc2_b[nt * 16 + cl];
      #pragma unroll
      for (int mt = 0; mt < 2; ++mt)
        #pragma unroll
        for (int r = 0; r < 4; ++r)
          out[(size_t)nr[mt][r] * CC + nt * 16 + cl] = x1v[j][mt][r] + acc2[j][mt][r] + bc;
    }
  }
}

extern "C" void kernel_launch(void* const* d_in, const int* in_sizes, int n_in,
                              void* d_out, int out_size, void* d_ws, size_t ws_size,
                              hipStream_t stream) {
  const float* x      = (const float*)d_in[0];
  const float* g1     = (const float*)d_in[1];
  const float* b1     = (const float*)d_in[2];
  const float* qkv_w  = (const float*)d_in[3];
  const float* qkv_b  = (const float*)d_in[4];
  const float* rpb    = (const float*)d_in[5];
  const float* proj_w = (const float*)d_in[6];
  const float* proj_b = (const float*)d_in[7];
  const float* g2     = (const float*)d_in[8];
  const float* b2     = (const float*)d_in[9];
  const float* fc1_w  = (const float*)d_in[10];
  const float* fc1_b  = (const float*)d_in[11];
  const float* fc2_w  = (const float*)d_in[12];
  const float* fc2_b  = (const float*)d_in[13];

  char* ws = (char*)d_ws;
  u16*   att    = (u16*)ws;                                   // NTOK*96 bf16 = 38.5 MB
  u16*   xnw    = (u16*)(ws + (size_t)NTOK * CC * 2);         // NWIN*112*96 bf16 = 44 MB
  char*  wtail  = ws + (size_t)NTOK * CC * 2 + (size_t)NWIN * 112 * CC * 2;
  float* biasT  = (float*)wtail;                              // 115248 B
  u16*   qkv_wT = (u16*)(wtail + 115248);                     // 55296 B
  u16*   proj_wT= (u16*)(wtail + 115248 + 55296);             // 18432 B
  u16*   fc1_wT = (u16*)(wtail + 115248 + 55296 + 18432);     // 73728 B
  u16*   fc2_wT = (u16*)(wtail + 115248 + 55296 + 18432 + 73728); // 73728 B

  wprep_kernel<<<(27648 + 9216 + 36864 + 36864 + 255) / 256, 256, 0, stream>>>(
      qkv_w, proj_w, fc1_w, fc2_w, qkv_wT, proj_wT, fc1_wT, fc2_wT);
  bias_kernel<<<(NHEADS * NN * NN + 255) / 256, 256, 0, stream>>>(rpb, biasT);
  ln1_kernel<<<NWIN * 112 / 64, 256, 0, stream>>>(x, g1, b1, xnw);
  attn_kernel<<<NWIN * NHEADS, 256, 0, stream>>>(xnw, qkv_wT, qkv_b, biasT, att);
  pm_kernel<<<NTOK / 32, 128, 0, stream>>>(att, proj_wT, proj_b, x, g2, b2,
                                           fc1_wT, fc1_b, fc2_wT, fc2_b, (float*)d_out);
}